// Round 7
// baseline (597.797 us; speedup 1.0000x reference)
//
#include <hip/hip_runtime.h>
#include <hip/hip_bf16.h>
#include <cmath>

#define T_ 1024
#define HID_ 2048
#define H_ 16
#define LQ_ 1536
#define LKV_ 512
#define DR_ 64
#define DN_ 128
#define DQ_ 192
#define DV_ 128
#define HI_ 16
#define DI_ 128
#define TOPK_ 256
#define NEGF (-1e30f)

typedef short bfrag_t __attribute__((ext_vector_type(8)));   // 8 bf16 = 4 VGPRs
typedef float f32x4 __attribute__((ext_vector_type(4)));

__device__ __forceinline__ float wave_sum64(float v) {
#pragma unroll
  for (int off = 32; off; off >>= 1) v += __shfl_xor(v, off);
  return v;
}

#define GLL(g, l) __builtin_amdgcn_global_load_lds((const __attribute__((address_space(1))) void*)(g), \
                                     (__attribute__((address_space(3))) void*)(l), 16, 0, 0)

// ================= zero fill (for split-K atomic accumulation) =================
__global__ __launch_bounds__(256) void zero_k(float4* __restrict__ p, int n4) {
  int i = blockIdx.x * 256 + threadIdx.x;
  if (i < n4) p[i] = make_float4(0.f, 0.f, 0.f, 0.f);
}

// ================= bf16 MFMA GEMM: C = A @ B^T — double-buffered, raw-barrier pipeline ====
template<typename CT>
__global__ __launch_bounds__(256) void gemm_bf_k(
    const short* __restrict__ A, int lda, long long sA,
    const short* __restrict__ B, int ldb, long long sB,
    CT* __restrict__ C, int ldc, long long sC,
    int Nout, int K)
{
  __shared__ short As[2][128 * 32];
  __shared__ short Bs[2][128 * 32];
  A += (long long)blockIdx.z * sA;
  B += (long long)blockIdx.z * sB;
  C += (long long)blockIdx.z * sC;
  const int tid = threadIdx.x;
  const int bm = blockIdx.y * 128, bn = blockIdx.x * 128;
  const int wave = tid >> 6, lane = tid & 63;
  const int wm = (wave >> 1) * 64, wn = (wave & 1) * 64;
  const int sr = tid >> 2;
  const int scol = (tid & 3) * 8;
  const int m0 = lane & 15, koff = (lane >> 4) * 8;
  f32x4 acc[4][4] = {};
  const short* ga = A + (long long)(bm + sr) * lda + scol;
  const short* gb = B + (long long)(bn + sr) * ldb + scol;
#define STAGE_BF(buf, off) \
    GLL(ga + (off), As[buf] + tid * 8); GLL(ga + (off) + 64 * lda, As[buf] + tid * 8 + 2048); \
    GLL(gb + (off), Bs[buf] + tid * 8); GLL(gb + (off) + 64 * ldb, Bs[buf] + tid * 8 + 2048);
  const int niter = K >> 5;
  STAGE_BF(0, 0);
  for (int it = 0; it < niter; ++it) {
    const int cur = it & 1;
    if (it + 1 < niter) {
      STAGE_BF(cur ^ 1, (it + 1) * 32);
      asm volatile("s_waitcnt vmcnt(4)\ns_barrier" ::: "memory");
    } else {
      asm volatile("s_waitcnt vmcnt(0)\ns_barrier" ::: "memory");
    }
    bfrag_t af[4], bfv[4];
#pragma unroll
    for (int i = 0; i < 4; ++i)
      af[i] = *(const bfrag_t*)(As[cur] + (wm + i * 16 + m0) * 32 + koff);
#pragma unroll
    for (int j = 0; j < 4; ++j)
      bfv[j] = *(const bfrag_t*)(Bs[cur] + (wn + j * 16 + m0) * 32 + koff);
#pragma unroll
    for (int i = 0; i < 4; ++i)
#pragma unroll
      for (int j = 0; j < 4; ++j)
        acc[i][j] = __builtin_amdgcn_mfma_f32_16x16x32_bf16(af[i], bfv[j], acc[i][j], 0, 0, 0);
    asm volatile("s_barrier" ::: "memory");
  }
#undef STAGE_BF
  const int cr = (lane >> 4) * 4, cc = lane & 15;
#pragma unroll
  for (int i = 0; i < 4; ++i) {
    int row = bm + wm + i * 16 + cr;
#pragma unroll
    for (int j = 0; j < 4; ++j) {
      int col = bn + wn + j * 16 + cc;
      if (col < Nout) {
#pragma unroll
        for (int r = 0; r < 4; ++r)
          C[(long long)(row + r) * ldc + col] = (CT)(acc[i][j][r]);
      }
    }
  }
}

// ====== bf16 GEMM, fp32 out, split-K over blockIdx.z with atomic accumulate ======
__global__ __launch_bounds__(256) void gemm_bfs_k(
    const short* __restrict__ A, int lda,
    const short* __restrict__ B, int ldb,
    float* __restrict__ C, int ldc, int Nout, int K)
{
  __shared__ short As[2][128 * 32];
  __shared__ short Bs[2][128 * 32];
  const long long kbase = (long long)blockIdx.z * K;
  const int tid = threadIdx.x;
  const int bm = blockIdx.y * 128, bn = blockIdx.x * 128;
  const int wave = tid >> 6, lane = tid & 63;
  const int wm = (wave >> 1) * 64, wn = (wave & 1) * 64;
  const int sr = tid >> 2;
  const int scol = (tid & 3) * 8;
  const int m0 = lane & 15, koff = (lane >> 4) * 8;
  f32x4 acc[4][4] = {};
  const short* ga = A + (long long)(bm + sr) * lda + kbase + scol;
  const short* gb = B + (long long)(bn + sr) * ldb + kbase + scol;
#define STAGE_BS(buf, off) \
    GLL(ga + (off), As[buf] + tid * 8); GLL(ga + (off) + 64 * lda, As[buf] + tid * 8 + 2048); \
    GLL(gb + (off), Bs[buf] + tid * 8); GLL(gb + (off) + 64 * ldb, Bs[buf] + tid * 8 + 2048);
  const int niter = K >> 5;
  STAGE_BS(0, 0);
  for (int it = 0; it < niter; ++it) {
    const int cur = it & 1;
    if (it + 1 < niter) {
      STAGE_BS(cur ^ 1, (it + 1) * 32);
      asm volatile("s_waitcnt vmcnt(4)\ns_barrier" ::: "memory");
    } else {
      asm volatile("s_waitcnt vmcnt(0)\ns_barrier" ::: "memory");
    }
    bfrag_t af[4], bfv[4];
#pragma unroll
    for (int i = 0; i < 4; ++i)
      af[i] = *(const bfrag_t*)(As[cur] + (wm + i * 16 + m0) * 32 + koff);
#pragma unroll
    for (int j = 0; j < 4; ++j)
      bfv[j] = *(const bfrag_t*)(Bs[cur] + (wn + j * 16 + m0) * 32 + koff);
#pragma unroll
    for (int i = 0; i < 4; ++i)
#pragma unroll
      for (int j = 0; j < 4; ++j)
        acc[i][j] = __builtin_amdgcn_mfma_f32_16x16x32_bf16(af[i], bfv[j], acc[i][j], 0, 0, 0);
    asm volatile("s_barrier" ::: "memory");
  }
#undef STAGE_BS
  const int cr = (lane >> 4) * 4, cc = lane & 15;
#pragma unroll
  for (int i = 0; i < 4; ++i) {
    int row = bm + wm + i * 16 + cr;
#pragma unroll
    for (int j = 0; j < 4; ++j) {
      int col = bn + wn + j * 16 + cc;
      if (col < Nout) {
#pragma unroll
        for (int r = 0; r < 4; ++r)
          atomicAdd(&C[(long long)(row + r) * ldc + col], acc[i][j][r]);
      }
    }
  }
}

// ====== bf16x3 split GEMM (fp32-accurate) — double-buffered, split-K capable ======
__global__ __launch_bounds__(256) void gemm3_k(
    const short* __restrict__ Ah, const short* __restrict__ Al, int lda,
    const short* __restrict__ Bh, const short* __restrict__ Bl, int ldb,
    float* __restrict__ C, int ldc, int Nout, int K)
{
  __shared__ short Ahs[2][128 * 32];
  __shared__ short Als[2][128 * 32];
  __shared__ short Bhs[2][128 * 32];
  __shared__ short Bls[2][128 * 32];
  const long long kbase = (long long)blockIdx.z * K;
  const int tid = threadIdx.x;
  const int bm = blockIdx.y * 128, bn = blockIdx.x * 128;
  const int wave = tid >> 6, lane = tid & 63;
  const int wm = (wave >> 1) * 64, wn = (wave & 1) * 64;
  const int sr = tid >> 2;
  const int scol = (tid & 3) * 8;
  const int m0 = lane & 15, koff = (lane >> 4) * 8;
  f32x4 acc[4][4] = {};
  const short* gah = Ah + (long long)(bm + sr) * lda + kbase + scol;
  const short* gal = Al + (long long)(bm + sr) * lda + kbase + scol;
  const short* gbh = Bh + (long long)(bn + sr) * ldb + kbase + scol;
  const short* gbl = Bl + (long long)(bn + sr) * ldb + kbase + scol;
#define STAGE_3(buf, off) \
    GLL(gah + (off), Ahs[buf] + tid * 8); GLL(gah + (off) + 64 * lda, Ahs[buf] + tid * 8 + 2048); \
    GLL(gal + (off), Als[buf] + tid * 8); GLL(gal + (off) + 64 * lda, Als[buf] + tid * 8 + 2048); \
    GLL(gbh + (off), Bhs[buf] + tid * 8); GLL(gbh + (off) + 64 * ldb, Bhs[buf] + tid * 8 + 2048); \
    GLL(gbl + (off), Bls[buf] + tid * 8); GLL(gbl + (off) + 64 * ldb, Bls[buf] + tid * 8 + 2048);
  const int niter = K >> 5;
  STAGE_3(0, 0);
  for (int it = 0; it < niter; ++it) {
    const int cur = it & 1;
    if (it + 1 < niter) {
      STAGE_3(cur ^ 1, (it + 1) * 32);
      asm volatile("s_waitcnt vmcnt(8)\ns_barrier" ::: "memory");
    } else {
      asm volatile("s_waitcnt vmcnt(0)\ns_barrier" ::: "memory");
    }
    bfrag_t afh[4], afl[4], bfh[4], bfl[4];
#pragma unroll
    for (int i = 0; i < 4; ++i) {
      afh[i] = *(const bfrag_t*)(Ahs[cur] + (wm + i * 16 + m0) * 32 + koff);
      afl[i] = *(const bfrag_t*)(Als[cur] + (wm + i * 16 + m0) * 32 + koff);
    }
#pragma unroll
    for (int j = 0; j < 4; ++j) {
      bfh[j] = *(const bfrag_t*)(Bhs[cur] + (wn + j * 16 + m0) * 32 + koff);
      bfl[j] = *(const bfrag_t*)(Bls[cur] + (wn + j * 16 + m0) * 32 + koff);
    }
    // term-grouped: no back-to-back MFMAs on the same accumulator (per-acc fp32
    // add order unchanged: hh, hl, lh within each K-iter -> bit-identical)
#pragma unroll
    for (int i = 0; i < 4; ++i)
#pragma unroll
      for (int j = 0; j < 4; ++j)
        acc[i][j] = __builtin_amdgcn_mfma_f32_16x16x32_bf16(afh[i], bfh[j], acc[i][j], 0, 0, 0);
#pragma unroll
    for (int i = 0; i < 4; ++i)
#pragma unroll
      for (int j = 0; j < 4; ++j)
        acc[i][j] = __builtin_amdgcn_mfma_f32_16x16x32_bf16(afh[i], bfl[j], acc[i][j], 0, 0, 0);
#pragma unroll
    for (int i = 0; i < 4; ++i)
#pragma unroll
      for (int j = 0; j < 4; ++j)
        acc[i][j] = __builtin_amdgcn_mfma_f32_16x16x32_bf16(afl[i], bfh[j], acc[i][j], 0, 0, 0);
    asm volatile("s_barrier" ::: "memory");
  }
#undef STAGE_3
  const int cr = (lane >> 4) * 4, cc = lane & 15;
  const bool spl = (gridDim.z > 1);
#pragma unroll
  for (int i = 0; i < 4; ++i) {
    int row = bm + wm + i * 16 + cr;
#pragma unroll
    for (int j = 0; j < 4; ++j) {
      int col = bn + wn + j * 16 + cc;
      if (col < Nout) {
#pragma unroll
        for (int r = 0; r < 4; ++r) {
          if (spl) atomicAdd(&C[(long long)(row + r) * ldc + col], acc[i][j][r]);
          else     C[(long long)(row + r) * ldc + col] = acc[i][j][r];
        }
      }
    }
  }
}

// ================= casts / decompose =================
__global__ __launch_bounds__(256) void cast_bf16_k(const float* __restrict__ src,
                                                   __hip_bfloat16* __restrict__ dst, int n4) {
  int i = blockIdx.x * 256 + threadIdx.x;
  if (i >= n4) return;
  float4 v = ((const float4*)src)[i];
  union { ushort4 u; __hip_bfloat16 h[4]; } o;
  o.h[0] = __float2bfloat16(v.x); o.h[1] = __float2bfloat16(v.y);
  o.h[2] = __float2bfloat16(v.z); o.h[3] = __float2bfloat16(v.w);
  ((ushort4*)dst)[i] = o.u;
}

__global__ __launch_bounds__(256) void decomp_k(const float* __restrict__ src,
                                                __hip_bfloat16* __restrict__ hi,
                                                __hip_bfloat16* __restrict__ lo, int n4) {
  int i = blockIdx.x * 256 + threadIdx.x;
  if (i >= n4) return;
  float4 v = ((const float4*)src)[i];
  float f[4] = {v.x, v.y, v.z, v.w};
  union { ushort4 u; __hip_bfloat16 h[4]; } oh, ol;
#pragma unroll
  for (int j = 0; j < 4; ++j) {
    __hip_bfloat16 h = __float2bfloat16(f[j]);
    oh.h[j] = h;
    ol.h[j] = __float2bfloat16(f[j] - __bfloat162float(h));
  }
  ((ushort4*)hi)[i] = oh.u;
  ((ushort4*)lo)[i] = ol.u;
}

__global__ __launch_bounds__(256) void cast_pad_k(const float* __restrict__ src,
                                                  __hip_bfloat16* __restrict__ dst,
                                                  int N, int K4, int Npad) {
  int i = blockIdx.x * 256 + threadIdx.x;
  if (i >= Npad * K4) return;
  int r = i / K4;
  float4 v = make_float4(0.f, 0.f, 0.f, 0.f);
  if (r < N) v = ((const float4*)src)[i];
  union { ushort4 u; __hip_bfloat16 h[4]; } o;
  o.h[0] = __float2bfloat16(v.x); o.h[1] = __float2bfloat16(v.y);
  o.h[2] = __float2bfloat16(v.z); o.h[3] = __float2bfloat16(v.w);
  ((ushort4*)dst)[i] = o.u;
}

// w_kn transposed-cast via LDS 64x64 tile: dst[h][k][d] = w_kvb[(h*256+d)*512+k]
__global__ __launch_bounds__(256) void wkn_t_k(const float* __restrict__ wkvb,
                                               __hip_bfloat16* __restrict__ dst) {
  __shared__ float tile[64][65];
  const int h = blockIdx.z, k0 = blockIdx.y * 64, d0 = blockIdx.x * 64;
  const int c = threadIdx.x & 63, r0 = threadIdx.x >> 6;
#pragma unroll
  for (int rr = 0; rr < 16; ++rr) {
    int r = r0 + rr * 4;
    tile[r][c] = wkvb[((h * 256 + d0 + r) << 9) + k0 + c];  // coalesced (k fast)
  }
  __syncthreads();
#pragma unroll
  for (int rr = 0; rr < 16; ++rr) {
    int r = r0 + rr * 4;   // k-local
    dst[((h * 512 + k0 + r) << 7) + d0 + c] = __float2bfloat16(tile[c][r]); // coalesced (d fast)
  }
}

__global__ __launch_bounds__(256) void wv_cast_k(const float* __restrict__ wkvb,
                                                 __hip_bfloat16* __restrict__ dst) {
  int i = blockIdx.x * 256 + threadIdx.x;
  int k = i & 511, dv = (i >> 9) & 127, h = i >> 16;
  dst[i] = __float2bfloat16(wkvb[((h * 256 + 128 + dv) << 9) + k]);
}

// ================= RMSNorm in-place (fp32) =================
__global__ __launch_bounds__(256) void rms_inplace_k(float* x, const float* __restrict__ g,
                                                     int C) {
  int t = blockIdx.x, tid = threadIdx.x;
  float* row = x + (long long)t * C;
  float ss = 0.f;
  for (int i = tid; i < C; i += 256) { float v = row[i]; ss += v * v; }
  __shared__ float red[4];
  ss = wave_sum64(ss);
  if ((tid & 63) == 0) red[tid >> 6] = ss;
  __syncthreads();
  float sc = rsqrtf((red[0] + red[1] + red[2] + red[3]) / (float)C + 1e-6f);
  for (int i = tid; i < C; i += 256) row[i] = row[i] * sc * g[i];
}

// ================= skv build -> bf16; row T_ = 0 =================
__global__ __launch_bounds__(256) void skv_build_k(const float* __restrict__ ckv,
                                                   const float* __restrict__ g,
                                                   const float* __restrict__ cosb,
                                                   const float* __restrict__ sinb,
                                                   __hip_bfloat16* __restrict__ skv) {
  int t = blockIdx.x, tid = threadIdx.x;
  __hip_bfloat16* out = skv + (long long)t * 576;
  if (t == T_) { for (int i = tid; i < 576; i += 256) out[i] = __float2bfloat16(0.f); return; }
  const float* row = ckv + (long long)t * 576;
  float ss = 0.f;
  for (int i = tid; i < 512; i += 256) { float v = row[i]; ss += v * v; }
  __shared__ float red[4];
  ss = wave_sum64(ss);
  if ((tid & 63) == 0) red[tid >> 6] = ss;
  __syncthreads();
  float sc = rsqrtf((red[0] + red[1] + red[2] + red[3]) / 512.f + 1e-6f);
  for (int i = tid; i < 512; i += 256) out[i] = __float2bfloat16(row[i] * sc * g[i]);
  if (tid < 64) {
    int j = tid, j2 = tid & 31;
    float c = cosb[t * 64 + j], s = sinb[t * 64 + j];
    float a = row[512 + 2 * j2], b = row[512 + 2 * j2 + 1];
    out[512 + j] = __float2bfloat16((j < 32) ? (a * c - b * s) : (a * s + b * c));
  }
}

// ================= rope in-place on qi heads (fp32) =================
__global__ __launch_bounds__(64) void rope_qi_k(float* qi, const float* __restrict__ cosb,
                                                const float* __restrict__ sinb) {
  int b = blockIdx.x, t = b >> 4, j = threadIdx.x, j2 = j & 31;
  float* x = qi + (long long)b * DI_;
  float c = cosb[t * 64 + j], s = sinb[t * 64 + j];
  float a = x[2 * j2], bb = x[2 * j2 + 1];
  float o = (j < 32) ? (a * c - bb * s) : (a * s + bb * c);
  x[j] = o;
}

// ================= ki: LayerNorm then rope, in-place (fp32) =================
__global__ __launch_bounds__(128) void ki_ln_rope_k(float* kbuf, const float* __restrict__ w,
                                                    const float* __restrict__ bia,
                                                    const float* __restrict__ cosb,
                                                    const float* __restrict__ sinb) {
  int t = blockIdx.x, i = threadIdx.x;
  float* row = kbuf + (long long)t * DI_;
  float x = row[i];
  __shared__ float red[2];
  float s1 = wave_sum64(x);
  if ((i & 63) == 0) red[i >> 6] = s1;
  __syncthreads();
  float mean = (red[0] + red[1]) / 128.f;
  float d = x - mean;
  __syncthreads();
  float s2 = wave_sum64(d * d);
  if ((i & 63) == 0) red[i >> 6] = s2;
  __syncthreads();
  float var = (red[0] + red[1]) / 128.f;
  float y = d * rsqrtf(var + 1e-6f) * w[i] + bia[i];
  __shared__ float rowl[128];
  rowl[i] = y;
  __syncthreads();
  float outv = y;
  if (i < 64) {
    int j2 = i & 31;
    float c = cosb[t * 64 + i], s = sinb[t * 64 + i];
    float a = rowl[2 * j2], b = rowl[2 * j2 + 1];
    outv = (i < 32) ? (a * c - b * s) : (a * s + b * c);
  }
  row[i] = outv;
}

// ================= rope q_full tail (bf16 in) -> sq_bf[...,512:576] =================
__global__ __launch_bounds__(64) void rope_q_sq_k(const __hip_bfloat16* __restrict__ qfull,
                                                  const float* __restrict__ cosb,
                                                  const float* __restrict__ sinb,
                                                  __hip_bfloat16* __restrict__ sq) {
  int b = blockIdx.x, t = b >> 4, h = b & 15, j = threadIdx.x, j2 = j & 31;
  const __hip_bfloat16* x = qfull + (long long)t * 3072 + h * 192 + 128;
  float c = cosb[t * 64 + j], s = sinb[t * 64 + j];
  float a = __bfloat162float(x[2 * j2]), bb = __bfloat162float(x[2 * j2 + 1]);
  float o = (j < 32) ? (a * c - bb * s) : (a * s + bb * c);
  sq[((long long)t * H_ + h) * 576 + 512 + j] = __float2bfloat16(o);
}

// ================= w = hidden @ i_wproj.T (fp32) =================
__global__ __launch_bounds__(256) void wproj_k(const float* __restrict__ hidden,
                                               const float* __restrict__ wp,
                                               float* __restrict__ out) {
  int wave = threadIdx.x >> 6, lane = threadIdx.x & 63;
  int t = blockIdx.x * 4 + wave;
  const float4* x4 = (const float4*)(hidden + (long long)t * 2048);
  float acc[16] = {};
  for (int c = lane; c < 512; c += 64) {
    float4 xv = x4[c];
#pragma unroll
    for (int h = 0; h < 16; ++h) {
      float4 wv = ((const float4*)(wp + h * 2048))[c];
      acc[h] += xv.x * wv.x + xv.y * wv.y + xv.z * wv.z + xv.w * wv.w;
    }
  }
#pragma unroll
  for (int h = 0; h < 16; ++h) {
    float s = wave_sum64(acc[h]);
    if (lane == 0) out[t * 16 + h] = s;
  }
}

// ================= indexer scores: MFMA bf16x3, grid (4, T_), register-rich =================
// launch_bounds (256,2): 128-VGPR budget so ah/al stay resident and 16 b-frag loads
// per tile-pair issue before any MFMA waits (R5's 36-VGPR build serialized reloads).
__global__ __launch_bounds__(256, 2) void score_k(
    const short* __restrict__ qi_hi, const short* __restrict__ qi_lo,
    const short* __restrict__ ki_hi, const short* __restrict__ ki_lo,
    const float* __restrict__ wproj, const int* __restrict__ ks,
    const int* __restrict__ ke, float* __restrict__ scores)
{
  __shared__ float s_w[HI_];
  const int seg = blockIdx.x, t = blockIdx.y, tid = threadIdx.x;
  const int wave = tid >> 6, lane = tid & 63;
  const int m0 = lane & 15, quad = lane >> 4;
  if (tid < HI_) s_w[tid] = wproj[t * HI_ + tid] * 0.022097086912079608f;
  __syncthreads();

  bfrag_t ah[4], al[4];
  {
    const short* qh = qi_hi + ((long long)t * HI_ + m0) * DI_ + quad * 8;
    const short* ql = qi_lo + ((long long)t * HI_ + m0) * DI_ + quad * 8;
#pragma unroll
    for (int k = 0; k < 4; ++k) {
      ah[k] = *(const bfrag_t*)(qh + k * 32);
      al[k] = *(const bfrag_t*)(ql + k * 32);
    }
  }
  const int lo = ks[t], hi = ke[t];
  float* srow = scores + t * T_;
#pragma unroll
  for (int tp = 0; tp < 2; ++tp) {
    const int n0 = seg * 256 + wave * 64 + tp * 32;        // tile pair: rows n0..n0+15, n0+16..n0+31
    const short* kh0 = ki_hi + (n0 + m0) * DI_ + quad * 8;
    const short* kl0 = ki_lo + (n0 + m0) * DI_ + quad * 8;
    const short* kh1 = kh0 + 16 * DI_;
    const short* kl1 = kl0 + 16 * DI_;
    bfrag_t bh0[4], bl0[4], bh1[4], bl1[4];
#pragma unroll
    for (int k = 0; k < 4; ++k) {       // 16 independent loads in flight
      bh0[k] = *(const bfrag_t*)(kh0 + k * 32);
      bl0[k] = *(const bfrag_t*)(kl0 + k * 32);
      bh1[k] = *(const bfrag_t*)(kh1 + k * 32);
      bl1[k] = *(const bfrag_t*)(kl1 + k * 32);
    }
    f32x4 acc0 = {0.f, 0.f, 0.f, 0.f};
    f32x4 acc1 = {0.f, 0.f, 0.f, 0.f};
#pragma unroll
    for (int k = 0; k < 4; ++k) {       // two independent accumulator chains
      acc0 = __builtin_amdgcn_mfma_f32_16x16x32_bf16(ah[k], bh0[k], acc0, 0, 0, 0);
      acc1 = __builtin_amdgcn_mfma_f32_16x16x32_bf16(ah[k], bh1[k], acc1, 0, 0, 0);
      acc0 = __builtin_amdgcn_mfma_f32_16x16x32_bf16(ah[k], bl0[k], acc0, 0, 0, 0);
      acc1 = __builtin_amdgcn_mfma_f32_16x16x32_bf16(ah[k], bl1[k], acc1, 0, 0, 0);
      acc0 = __builtin_amdgcn_mfma_f32_16x16x32_bf16(al[k], bh0[k], acc0, 0, 0, 0);
      acc1 = __builtin_amdgcn_mfma_f32_16x16x32_bf16(al[k], bh1[k], acc1, 0, 0, 0);
    }
    float sc0 = 0.f, sc1 = 0.f;
#pragma unroll
    for (int r = 0; r < 4; ++r) {
      float w = s_w[quad * 4 + r];
      sc0 += fmaxf(acc0[r], 0.f) * w;
      sc1 += fmaxf(acc1[r], 0.f) * w;
    }
    sc0 += __shfl_xor(sc0, 16); sc0 += __shfl_xor(sc0, 32);
    sc1 += __shfl_xor(sc1, 16); sc1 += __shfl_xor(sc1, 32);
    if (quad == 0) {
      int key0 = n0 + m0, key1 = n0 + 16 + m0;
      srow[key0] = (key0 >= lo && key0 <= hi) ? sc0 : NEGF;
      srow[key1] = (key1 >= lo && key1 <= hi) ? sc1 : NEGF;
    }
  }
}

// ========== exact radix-select top-256 — keys in registers, ballot-aggregated atomics ======
__global__ __launch_bounds__(256) void topk_k(const float* __restrict__ scores,
                                              int* __restrict__ indices)
{
  __shared__ unsigned s_hist[256];
  __shared__ unsigned s_wsum[4];
  __shared__ unsigned s_binsel[2];
  __shared__ unsigned s_cnt;
  const int t = blockIdx.x, tid = threadIdx.x;
  const int wave = tid >> 6, lane = tid & 63;
  const int i0 = tid * 4;
  if (tid == 0) s_cnt = 0;

  float4 sv = ((const float4*)(scores + t * T_))[tid];
  float f[4] = {sv.x, sv.y, sv.z, sv.w};
  unsigned key[4];
#pragma unroll
  for (int j = 0; j < 4; ++j) {
    unsigned u = __float_as_uint(f[j]);
    key[j] = (u & 0x80000000u) ? ~u : (u | 0x80000000u);
  }

  unsigned prefix = 0, Gprev = 0;
  for (int lvl = 0; lvl < 4; ++lvl) {
    const int shift = 24 - 8 * lvl;
    s_hist[tid] = 0;
    __syncthreads();
#pragma unroll
    for (int j = 0; j < 4; ++j) {
      unsigned k = key[j];
      bool part = (lvl == 0) || ((k >> (shift + 8)) == prefix);
      unsigned bin = (k >> shift) & 255u;
      unsigned long long mask = __ballot(part);
#pragma unroll
      for (int b = 0; b < 8; ++b) {
        unsigned long long bal = __ballot((bin >> b) & 1u);
        mask &= ((bin >> b) & 1u) ? bal : ~bal;
      }
      if (part && lane == (__ffsll((long long)mask) - 1))
        atomicAdd(&s_hist[bin], (unsigned)__popcll(mask));
    }
    __syncthreads();
    unsigned h = s_hist[255 - tid];
    unsigned sc_ = h;
    for (int off = 1; off < 64; off <<= 1) {
      unsigned v = __shfl_up(sc_, off);
      if (lane >= off) sc_ += v;
    }
    if (lane == 63) s_wsum[wave] = sc_;
    __syncthreads();
    unsigned wo = 0;
    for (int w = 0; w < wave; ++w) wo += s_wsum[w];
    unsigned incl = sc_ + wo, excl = incl - h;
    unsigned Rn = 256 - Gprev;
    if (excl < Rn && Rn <= incl) { s_binsel[0] = 255 - (unsigned)tid; s_binsel[1] = excl; }
    __syncthreads();
    prefix = (prefix << 8) | s_binsel[0];
    Gprev += s_binsel[1];
  }
  const unsigned thr = prefix;
  const unsigned Rq = 256 - Gprev;
  const unsigned negfkey = ~__float_as_uint(NEGF);

  unsigned eqc = 0;
#pragma unroll
  for (int j = 0; j < 4; ++j) eqc += (key[j] == thr) ? 1u : 0u;
  unsigned esc = eqc;
  for (int off = 1; off < 64; off <<= 1) {
    unsigned v = __shfl_up(esc, off);
    if (lane >= off) esc += v;
  }
  if (lane == 63) s_wsum[wave] = esc;
  __syncthreads();
  unsigned eo = 0;
  for (int w = 0; w < wave; ++w) eo += s_wsum[w];
  unsigned rank = esc + eo - eqc;

#pragma unroll
  for (int j = 0; j < 4; ++j) {
    unsigned k = key[j];
    int outv = (k == negfkey) ? T_ : (i0 + j);
    bool gt = (k > thr);
    unsigned long long bal = __ballot(gt);
    if (bal) {
      int leader = __ffsll((long long)bal) - 1;
      unsigned base = 0;
      if (lane == leader) base = atomicAdd(&s_cnt, (unsigned)__popcll(bal));
      base = (unsigned)__shfl((int)base, leader);
      if (gt) {
        unsigned pre = (unsigned)__popcll(bal & ((1ull << lane) - 1ull));
        indices[t * TOPK_ + base + pre] = outv;
      }
    }
    if (!gt && k == thr) {
      if (rank < Rq) indices[t * TOPK_ + Gprev + rank] = outv;
      rank++;
    }
  }
}

// ========= MFMA gathered attention — 512 thr, 2 PV wave-groups, XOR-swizzled V-LDS =========
#define SP_LD 257
#define PB_LD 264
#define VT_LD 264
__global__ __launch_bounds__(512) void attn_k(
    const short* __restrict__ sq, const short* __restrict__ skv,
    const int* __restrict__ indices, __hip_bfloat16* __restrict__ attn_out)
{
  __shared__ int s_ind[TOPK_];
  __shared__ __align__(16) char s_un[2 * 64 * VT_LD * 2];  // 67584 B
  float* s_p  = (float*)s_un;                 // [H_][SP_LD] = 16448 B (QK..pack phase)
  short* s_pb = (short*)(s_un + 16448);       // [H_][PB_LD] =  8448 B (disjoint from s_p)
  short* s_vt = (short*)s_un;                 // [2][64][VT_LD] (PV phase)
  const int t = blockIdx.x, tid = threadIdx.x;
  const int wave = tid >> 6, lane = tid & 63;
  const int m0 = lane & 15, quad = lane >> 4;
  if (tid < TOPK_) s_ind[tid] = indices[t * TOPK_ + tid];
  __syncthreads();

  // ---- QK^T: each wave owns 32 KV rows ----
  {
    const int jb = wave * 32;
    int rows[2];
    const short* kvp[2];
#pragma unroll
    for (int j = 0; j < 2; ++j) {
      rows[j] = s_ind[jb + j * 16 + m0];
      kvp[j] = skv + rows[j] * 576 + quad * 8;
    }
    const short* qp = sq + ((long long)t * H_ + m0) * 576 + quad * 8;
    f32x4 qacc[2] = {};
    for (int ks = 0; ks < 18; ++ks) {
      const int k0 = ks * 32;
      bfrag_t aq = *(const bfrag_t*)(qp + k0);
#pragma unroll
      for (int j = 0; j < 2; ++j) {
        bfrag_t bq = *(const bfrag_t*)(kvp[j] + k0);
        qacc[j] = __builtin_amdgcn_mfma_f32_16x16x32_bf16(aq, bq, qacc[j], 0, 0, 0);
      }
    }
    const float scale = 0.07216878364870322f;
#pragma unroll
    for (int j = 0; j < 2; ++j) {
      int key = jb + j * 16 + m0;
      bool msk = (rows[j] == T_);
#pragma unroll
      for (int r = 0; r < 4; ++r)
        s_p[(quad * 4 + r) * SP_LD + key] = msk ? NEGF : qacc[j][r] * scale;
    }
  }
  __syncthreads();

  // ---- softmax (2 heads per wave) ----
  for (int h = wave * 2; h < wave * 2 + 2; ++h) {
    float* ph = s_p + h * SP_LD;
    float m = -3.4e38f;
    for (int j = lane; j < TOPK_; j += 64) m = fmaxf(m, ph[j]);
#pragma unroll
    for (int off = 32; off; off >>= 1) m = fmaxf(m, __shfl_xor(m, off));
    float sum = 0.f;
    for (int j = lane; j < TOPK_; j += 64) {
      float e = __expf(ph[j] - m);
      ph[j] = e; sum += e;
    }
    sum = wave_sum64(sum);
    float inv = 1.f / sum;
    for (int j = lane; j < TOPK_; j += 64) ph[j] *= inv;
  }
  __syncthreads();

  // ---- pack P -> bf16 (s_pb disjoint from s_p) ----
  {
    const int col = tid & 255, h0 = tid >> 8;
#pragma unroll
    for (int h = 0; h < 8; ++h) {
      const int hh = h0 + h * 2;
      s_pb[hh * PB_LD + col] =
          (short)__bfloat16_as_ushort(__float2bfloat16(s_p[hh * SP_LD + col]));
    }
  }
  __syncthreads();

  bfrag_t apf[8];
#pragma unroll
  for (int kk = 0; kk < 8; ++kk)
    apf[kk] = *(const bfrag_t*)(s_pb + m0 * PB_LD + kk * 32 + quad * 8);

  // ---- PV: group = wave>>2 handles c in [grp*4, grp*4+4) with its own s_vt ----
  const int grp = wave >> 2, gw = wave & 3;
  short* svt = s_vt + grp * (64 * VT_LD);
  const int r8 = (tid >> 3) & 31;   // row slot within 256-thread group
  const int bb = tid & 7;           // 16B chunk within the 128B slab

  for (int cc = 0; cc < 4; ++cc) {
    const int c = grp * 4 + cc;
    __syncthreads();   // apf reads (first iter) / prev MFMA reads done; safe to overwrite svt
#pragma unroll
    for (int rep = 0; rep < 8; ++rep) {
      const int kv = r8 + 32 * rep;
      const int row = s_ind[kv];
      bfrag_t v = *(const bfrag_t*)(skv + (long long)row * 576 + c * 64 + bb * 8);
      const int colx = kv ^ (bb << 3);
#pragma unroll
      for (int j = 0; j < 8; ++j)
        svt[(bb * 8 + j) * VT_LD + colx] = v[j];
    }
    __syncthreads();
    const int d = gw * 16 + m0;
    const short* vrow = svt + d * VT_LD;
    const int sx = (d >> 3) << 3;
    f32x4 oacc = {0.f, 0.f, 0.f, 0.f};
#pragma unroll
    for (int kk = 0; kk < 8; ++kk) {
      bfrag_t bv = *(const bfrag_t*)(vrow + ((kk * 32 + quad * 8) ^ sx));
      oacc = __builtin_amdgcn_mfma_f32_16x16x32_bf16(apf[kk], bv, oacc, 0, 0, 0);
    }
    const int col = c * 64 + d;
#pragma unroll
    for (int r = 0; r < 4; ++r)
      attn_out[((long long)t * H_ + quad * 4 + r) * 512 + col] = __float2bfloat16(oacc[r]);
  }
}

extern "C" void kernel_launch(void* const* d_in, const int* in_sizes, int n_in,
                              void* d_out, int out_size, void* d_ws, size_t ws_size,
                              hipStream_t stream) {
  const float* hidden  = (const float*)d_in[0];
  const float* cosb    = (const float*)d_in[1];
  const float* sinb    = (const float*)d_in[2];
  const int*   ks      = (const int*)d_in[3];
  const int*   ke      = (const int*)d_in[4];
  const float* w_qa    = (const float*)d_in[5];
  const float* g_qa    = (const float*)d_in[6];
  const float* w_qb    = (const float*)d_in[7];
  const float* w_kva   = (const float*)d_in[8];
  const float* g_kva   = (const float*)d_in[9];
  const float* w_kvb   = (const float*)d_in[10];
  const float* w_o     = (const float*)d_in[11];
  const float* i_wqb   = (const float*)d_in[12];
  const float* i_wk    = (const float*)d_in[13];
  const float* i_ln_w  = (const float*)d_in[14];
  const float* i_ln_b  = (const float*)d_in[15];
  const float* i_wproj = (const float*)d_in[16];
  float* out = (float*)d_out;
  (void)in_sizes; (void)n_in; (void)out_size; (void)ws_size;

  // ---- workspace (bytes), lifetime-overlapped (layout verified R6) ----
  char* ws = (char*)d_ws;
  __hip_bfloat16* hid_hi  = (__hip_bfloat16*)(ws + 0);
  __hip_bfloat16* hid_lo  = (__hip_bfloat16*)(ws + 4194304);
  float*          q_lat   = (float*)(ws + 8388608);
  __hip_bfloat16* qi_hi   = (__hip_bfloat16*)(ws + 8388608);    // over dead q_lat
  __hip_bfloat16* qlat_hi = (__hip_bfloat16*)(ws + 14680064);
  __hip_bfloat16* qlat_lo = (__hip_bfloat16*)(ws + 17825792);
  float*          qi      = (float*)(ws + 20971520);
  float*          scoresb = (float*)(ws + 20971520);            // over dead qi (post-decomp)
  float*          kib     = (float*)(ws + 29360128);
  float*          wbuf    = (float*)(ws + 29884416);
  float*          ckv     = (float*)(ws + 29949952);
  __hip_bfloat16* qi_lo   = (__hip_bfloat16*)(ws + 29949952);   // over dead ckv
  __hip_bfloat16* ki_hi   = (__hip_bfloat16*)(ws + 34144256);
  __hip_bfloat16* ki_lo   = (__hip_bfloat16*)(ws + 34406400);
  __hip_bfloat16* sq_bf   = (__hip_bfloat16*)(ws + 0);
  __hip_bfloat16* o_bf    = (__hip_bfloat16*)(ws + 0);
  __hip_bfloat16* W       = (__hip_bfloat16*)(ws + 37748736);
  __hip_bfloat16* skv_bf  = (__hip_bfloat16*)(ws + 47185920);
  int*            idxb    = (int*)(ws + 48366720);
  __hip_bfloat16* E       = (__hip_bfloat16*)(ws + 49415296);

  dim3 blk(256);
  const short* Ws = (const short*)W;
  const short* Es = (const short*)E;

  decomp_k<<<2048, blk, 0, stream>>>(hidden, hid_hi, hid_lo, 524288);

  // ---- q_lat = hidden @ w_qa^T (split-K=4: 384 blocks) ----
  decomp_k<<<3072, blk, 0, stream>>>(w_qa, W, E, 786432);
  zero_k<<<1536, blk, 0, stream>>>((float4*)q_lat, 393216);
  gemm3_k<<<dim3(12, 8, 4), blk, 0, stream>>>(
      (const short*)hid_hi, (const short*)hid_lo, HID_, Ws, Es, HID_, q_lat, LQ_, LQ_, 512);
  rms_inplace_k<<<T_, blk, 0, stream>>>(q_lat, g_qa, LQ_);

  // ---- ckv = hidden @ w_kva^T (split-K=4: 160 blocks) ----
  cast_pad_k<<<1280, blk, 0, stream>>>(w_kva, W, 576, 512, 640);
  zero_k<<<576, blk, 0, stream>>>((float4*)ckv, 147456);
  gemm_bfs_k<<<dim3(5, 8, 4), blk, 0, stream>>>(
      (const short*)hid_hi, HID_, Ws, HID_, ckv, 576, 576, 512);
  skv_build_k<<<T_ + 1, blk, 0, stream>>>(ckv, g_kva, cosb, sinb, skv_bf);

  decomp_k<<<1536, blk, 0, stream>>>(q_lat, qlat_hi, qlat_lo, 393216);

  // ---- qi = q_lat @ i_wqb^T (split-K=4: 512 blocks) ----
  decomp_k<<<3072, blk, 0, stream>>>(i_wqb, W, E, 786432);
  zero_k<<<2048, blk, 0, stream>>>((float4*)qi, 524288);
  gemm3_k<<<dim3(16, 8, 4), blk, 0, stream>>>(
      (const short*)qlat_hi, (const short*)qlat_lo, LQ_, Ws, Es, LQ_, qi, HI_ * DI_, HI_ * DI_, 384);
  rope_qi_k<<<T_ * HI_, dim3(64), 0, stream>>>(qi, cosb, sinb);
  decomp_k<<<2048, blk, 0, stream>>>(qi, qi_hi, qi_lo, 524288);

  // ---- kib = hidden @ i_wk^T (split-K=16: 128 blocks) ----
  decomp_k<<<256, blk, 0, stream>>>(i_wk, W, E, 65536);
  zero_k<<<128, blk, 0, stream>>>((float4*)kib, 32768);
  gemm3_k<<<dim3(1, 8, 16), blk, 0, stream>>>(
      (const short*)hid_hi, (const short*)hid_lo, HID_, Ws, Es, HID_, kib, DI_, DI_, 128);
  ki_ln_rope_k<<<T_, dim3(128), 0, stream>>>(kib, i_ln_w, i_ln_b, cosb, sinb);
  decomp_k<<<128, blk, 0, stream>>>(kib, ki_hi, ki_lo, 32768);

  wproj_k<<<256, blk, 0, stream>>>(hidden, i_wproj, wbuf);

  // ---- indexer: scores (4096 blocks) then register-key radix select ----
  score_k<<<dim3(4, T_), blk, 0, stream>>>(
      (const short*)qi_hi, (const short*)qi_lo, (const short*)ki_hi, (const short*)ki_lo,
      wbuf, ks, ke, scoresb);
  topk_k<<<T_, blk, 0, stream>>>(scoresb, idxb);

  cast_bf16_k<<<4608, blk, 0, stream>>>(w_qb, W, 1179648);
  gemm_bf_k<__hip_bfloat16><<<dim3(24, 8, 1), blk, 0, stream>>>(
      (const short*)qlat_hi, LQ_, 0, Ws, LQ_, 0, (__hip_bfloat16*)E, H_ * DQ_, 0, H_ * DQ_, LQ_);
  rope_q_sq_k<<<T_ * H_, dim3(64), 0, stream>>>(E, cosb, sinb, sq_bf);

  wkn_t_k<<<dim3(2, 8, 16), blk, 0, stream>>>(w_kvb, W);
  gemm_bf_k<__hip_bfloat16><<<dim3(4, 8, 16), blk, 0, stream>>>(
      Es, H_ * DQ_, 192, Ws, DI_, 65536, sq_bf, H_ * 576, 576, LKV_, DN_);

  attn_k<<<T_, dim3(512), 0, stream>>>((const short*)sq_bf, (const short*)skv_bf, idxb, E);

  wv_cast_k<<<4096, blk, 0, stream>>>(w_kvb, W);
  gemm_bf_k<__hip_bfloat16><<<dim3(1, 8, 16), blk, 0, stream>>>(
      Es, H_ * LKV_, 512, Ws, LKV_, 65536, o_bf, H_ * DV_, 128, DV_, LKV_);

  // ---- out = o_bf @ w_o^T (split-K=4: 512 blocks) ----
  cast_bf16_k<<<4096, blk, 0, stream>>>(w_o, W, 1048576);
  zero_k<<<2048, blk, 0, stream>>>((float4*)out, 524288);
  gemm_bfs_k<<<dim3(16, 8, 4), blk, 0, stream>>>(
      (const short*)o_bf, H_ * DV_, Ws, H_ * DV_, out, HID_, HID_, 512);
}

// Round 8
// 542.628 us; speedup vs baseline: 1.1017x; 1.1017x over previous
//
#include <hip/hip_runtime.h>
#include <hip/hip_bf16.h>
#include <cmath>

#define T_ 1024
#define HID_ 2048
#define H_ 16
#define LQ_ 1536
#define LKV_ 512
#define DR_ 64
#define DN_ 128
#define DQ_ 192
#define DV_ 128
#define HI_ 16
#define DI_ 128
#define TOPK_ 256
#define NEGF (-1e30f)

typedef short bfrag_t __attribute__((ext_vector_type(8)));   // 8 bf16 = 4 VGPRs
typedef float f32x4 __attribute__((ext_vector_type(4)));

__device__ __forceinline__ float wave_sum64(float v) {
#pragma unroll
  for (int off = 32; off; off >>= 1) v += __shfl_xor(v, off);
  return v;
}

#define GLL(g, l) __builtin_amdgcn_global_load_lds((const __attribute__((address_space(1))) void*)(g), \
                                     (__attribute__((address_space(3))) void*)(l), 16, 0, 0)

// ================= zero fill (for split-K atomic accumulation) =================
__global__ __launch_bounds__(256) void zero_k(float4* __restrict__ p, int n4) {
  int i = blockIdx.x * 256 + threadIdx.x;
  if (i < n4) p[i] = make_float4(0.f, 0.f, 0.f, 0.f);
}

// ================= bf16 MFMA GEMM: C = A @ B^T — double-buffered, raw-barrier pipeline ====
template<typename CT>
__global__ __launch_bounds__(256) void gemm_bf_k(
    const short* __restrict__ A, int lda, long long sA,
    const short* __restrict__ B, int ldb, long long sB,
    CT* __restrict__ C, int ldc, long long sC,
    int Nout, int K)
{
  __shared__ short As[2][128 * 32];
  __shared__ short Bs[2][128 * 32];
  A += (long long)blockIdx.z * sA;
  B += (long long)blockIdx.z * sB;
  C += (long long)blockIdx.z * sC;
  const int tid = threadIdx.x;
  const int bm = blockIdx.y * 128, bn = blockIdx.x * 128;
  const int wave = tid >> 6, lane = tid & 63;
  const int wm = (wave >> 1) * 64, wn = (wave & 1) * 64;
  const int sr = tid >> 2;
  const int scol = (tid & 3) * 8;
  const int m0 = lane & 15, koff = (lane >> 4) * 8;
  f32x4 acc[4][4] = {};
  const short* ga = A + (long long)(bm + sr) * lda + scol;
  const short* gb = B + (long long)(bn + sr) * ldb + scol;
#define STAGE_BF(buf, off) \
    GLL(ga + (off), As[buf] + tid * 8); GLL(ga + (off) + 64 * lda, As[buf] + tid * 8 + 2048); \
    GLL(gb + (off), Bs[buf] + tid * 8); GLL(gb + (off) + 64 * ldb, Bs[buf] + tid * 8 + 2048);
  const int niter = K >> 5;
  STAGE_BF(0, 0);
  for (int it = 0; it < niter; ++it) {
    const int cur = it & 1;
    if (it + 1 < niter) {
      STAGE_BF(cur ^ 1, (it + 1) * 32);
      asm volatile("s_waitcnt vmcnt(4)\ns_barrier" ::: "memory");
    } else {
      asm volatile("s_waitcnt vmcnt(0)\ns_barrier" ::: "memory");
    }
    bfrag_t af[4], bfv[4];
#pragma unroll
    for (int i = 0; i < 4; ++i)
      af[i] = *(const bfrag_t*)(As[cur] + (wm + i * 16 + m0) * 32 + koff);
#pragma unroll
    for (int j = 0; j < 4; ++j)
      bfv[j] = *(const bfrag_t*)(Bs[cur] + (wn + j * 16 + m0) * 32 + koff);
#pragma unroll
    for (int i = 0; i < 4; ++i)
#pragma unroll
      for (int j = 0; j < 4; ++j)
        acc[i][j] = __builtin_amdgcn_mfma_f32_16x16x32_bf16(af[i], bfv[j], acc[i][j], 0, 0, 0);
    asm volatile("s_barrier" ::: "memory");
  }
#undef STAGE_BF
  const int cr = (lane >> 4) * 4, cc = lane & 15;
#pragma unroll
  for (int i = 0; i < 4; ++i) {
    int row = bm + wm + i * 16 + cr;
#pragma unroll
    for (int j = 0; j < 4; ++j) {
      int col = bn + wn + j * 16 + cc;
      if (col < Nout) {
#pragma unroll
        for (int r = 0; r < 4; ++r)
          C[(long long)(row + r) * ldc + col] = (CT)(acc[i][j][r]);
      }
    }
  }
}

// ====== bf16 GEMM, fp32 out, split-K over blockIdx.z with atomic accumulate ======
__global__ __launch_bounds__(256) void gemm_bfs_k(
    const short* __restrict__ A, int lda,
    const short* __restrict__ B, int ldb,
    float* __restrict__ C, int ldc, int Nout, int K)
{
  __shared__ short As[2][128 * 32];
  __shared__ short Bs[2][128 * 32];
  const long long kbase = (long long)blockIdx.z * K;
  const int tid = threadIdx.x;
  const int bm = blockIdx.y * 128, bn = blockIdx.x * 128;
  const int wave = tid >> 6, lane = tid & 63;
  const int wm = (wave >> 1) * 64, wn = (wave & 1) * 64;
  const int sr = tid >> 2;
  const int scol = (tid & 3) * 8;
  const int m0 = lane & 15, koff = (lane >> 4) * 8;
  f32x4 acc[4][4] = {};
  const short* ga = A + (long long)(bm + sr) * lda + kbase + scol;
  const short* gb = B + (long long)(bn + sr) * ldb + kbase + scol;
#define STAGE_BS(buf, off) \
    GLL(ga + (off), As[buf] + tid * 8); GLL(ga + (off) + 64 * lda, As[buf] + tid * 8 + 2048); \
    GLL(gb + (off), Bs[buf] + tid * 8); GLL(gb + (off) + 64 * ldb, Bs[buf] + tid * 8 + 2048);
  const int niter = K >> 5;
  STAGE_BS(0, 0);
  for (int it = 0; it < niter; ++it) {
    const int cur = it & 1;
    if (it + 1 < niter) {
      STAGE_BS(cur ^ 1, (it + 1) * 32);
      asm volatile("s_waitcnt vmcnt(4)\ns_barrier" ::: "memory");
    } else {
      asm volatile("s_waitcnt vmcnt(0)\ns_barrier" ::: "memory");
    }
    bfrag_t af[4], bfv[4];
#pragma unroll
    for (int i = 0; i < 4; ++i)
      af[i] = *(const bfrag_t*)(As[cur] + (wm + i * 16 + m0) * 32 + koff);
#pragma unroll
    for (int j = 0; j < 4; ++j)
      bfv[j] = *(const bfrag_t*)(Bs[cur] + (wn + j * 16 + m0) * 32 + koff);
#pragma unroll
    for (int i = 0; i < 4; ++i)
#pragma unroll
      for (int j = 0; j < 4; ++j)
        acc[i][j] = __builtin_amdgcn_mfma_f32_16x16x32_bf16(af[i], bfv[j], acc[i][j], 0, 0, 0);
    asm volatile("s_barrier" ::: "memory");
  }
#undef STAGE_BS
  const int cr = (lane >> 4) * 4, cc = lane & 15;
#pragma unroll
  for (int i = 0; i < 4; ++i) {
    int row = bm + wm + i * 16 + cr;
#pragma unroll
    for (int j = 0; j < 4; ++j) {
      int col = bn + wn + j * 16 + cc;
      if (col < Nout) {
#pragma unroll
        for (int r = 0; r < 4; ++r)
          atomicAdd(&C[(long long)(row + r) * ldc + col], acc[i][j][r]);
      }
    }
  }
}

// ====== bf16x3 split GEMM (fp32-accurate) — double-buffered, split-K capable ======
__global__ __launch_bounds__(256) void gemm3_k(
    const short* __restrict__ Ah, const short* __restrict__ Al, int lda,
    const short* __restrict__ Bh, const short* __restrict__ Bl, int ldb,
    float* __restrict__ C, int ldc, int Nout, int K)
{
  __shared__ short Ahs[2][128 * 32];
  __shared__ short Als[2][128 * 32];
  __shared__ short Bhs[2][128 * 32];
  __shared__ short Bls[2][128 * 32];
  const long long kbase = (long long)blockIdx.z * K;
  const int tid = threadIdx.x;
  const int bm = blockIdx.y * 128, bn = blockIdx.x * 128;
  const int wave = tid >> 6, lane = tid & 63;
  const int wm = (wave >> 1) * 64, wn = (wave & 1) * 64;
  const int sr = tid >> 2;
  const int scol = (tid & 3) * 8;
  const int m0 = lane & 15, koff = (lane >> 4) * 8;
  f32x4 acc[4][4] = {};
  const short* gah = Ah + (long long)(bm + sr) * lda + kbase + scol;
  const short* gal = Al + (long long)(bm + sr) * lda + kbase + scol;
  const short* gbh = Bh + (long long)(bn + sr) * ldb + kbase + scol;
  const short* gbl = Bl + (long long)(bn + sr) * ldb + kbase + scol;
#define STAGE_3(buf, off) \
    GLL(gah + (off), Ahs[buf] + tid * 8); GLL(gah + (off) + 64 * lda, Ahs[buf] + tid * 8 + 2048); \
    GLL(gal + (off), Als[buf] + tid * 8); GLL(gal + (off) + 64 * lda, Als[buf] + tid * 8 + 2048); \
    GLL(gbh + (off), Bhs[buf] + tid * 8); GLL(gbh + (off) + 64 * ldb, Bhs[buf] + tid * 8 + 2048); \
    GLL(gbl + (off), Bls[buf] + tid * 8); GLL(gbl + (off) + 64 * ldb, Bls[buf] + tid * 8 + 2048);
  const int niter = K >> 5;
  STAGE_3(0, 0);
  for (int it = 0; it < niter; ++it) {
    const int cur = it & 1;
    if (it + 1 < niter) {
      STAGE_3(cur ^ 1, (it + 1) * 32);
      asm volatile("s_waitcnt vmcnt(8)\ns_barrier" ::: "memory");
    } else {
      asm volatile("s_waitcnt vmcnt(0)\ns_barrier" ::: "memory");
    }
    bfrag_t afh[4], afl[4], bfh[4], bfl[4];
#pragma unroll
    for (int i = 0; i < 4; ++i) {
      afh[i] = *(const bfrag_t*)(Ahs[cur] + (wm + i * 16 + m0) * 32 + koff);
      afl[i] = *(const bfrag_t*)(Als[cur] + (wm + i * 16 + m0) * 32 + koff);
    }
#pragma unroll
    for (int j = 0; j < 4; ++j) {
      bfh[j] = *(const bfrag_t*)(Bhs[cur] + (wn + j * 16 + m0) * 32 + koff);
      bfl[j] = *(const bfrag_t*)(Bls[cur] + (wn + j * 16 + m0) * 32 + koff);
    }
    // term-grouped: no back-to-back MFMAs on the same accumulator (per-acc fp32
    // add order unchanged: hh, hl, lh within each K-iter -> bit-identical)
#pragma unroll
    for (int i = 0; i < 4; ++i)
#pragma unroll
      for (int j = 0; j < 4; ++j)
        acc[i][j] = __builtin_amdgcn_mfma_f32_16x16x32_bf16(afh[i], bfh[j], acc[i][j], 0, 0, 0);
#pragma unroll
    for (int i = 0; i < 4; ++i)
#pragma unroll
      for (int j = 0; j < 4; ++j)
        acc[i][j] = __builtin_amdgcn_mfma_f32_16x16x32_bf16(afh[i], bfl[j], acc[i][j], 0, 0, 0);
#pragma unroll
    for (int i = 0; i < 4; ++i)
#pragma unroll
      for (int j = 0; j < 4; ++j)
        acc[i][j] = __builtin_amdgcn_mfma_f32_16x16x32_bf16(afl[i], bfh[j], acc[i][j], 0, 0, 0);
    asm volatile("s_barrier" ::: "memory");
  }
#undef STAGE_3
  const int cr = (lane >> 4) * 4, cc = lane & 15;
  const bool spl = (gridDim.z > 1);
#pragma unroll
  for (int i = 0; i < 4; ++i) {
    int row = bm + wm + i * 16 + cr;
#pragma unroll
    for (int j = 0; j < 4; ++j) {
      int col = bn + wn + j * 16 + cc;
      if (col < Nout) {
#pragma unroll
        for (int r = 0; r < 4; ++r) {
          if (spl) atomicAdd(&C[(long long)(row + r) * ldc + col], acc[i][j][r]);
          else     C[(long long)(row + r) * ldc + col] = acc[i][j][r];
        }
      }
    }
  }
}

// ====== indexer scores as a GEMM: logits = qi @ ki^T (bf16x3, M=16384 N=1024 K=128) ======
// GLL-pipelined (no VGPR-batched loads — R5/R6 showed the compiler serializes those).
// Fused epilogue: scores[t][s] = sum_h relu(logits[t*16+h][s]) * w[t][h] (+ validity mask).
// acc[i] rows = 16 heads of token (bm+wm+i*16)>>4; lane holds h = quad*4+r -> same
// relu-dot + shfl_xor(16,32) reduction as the previous score_k epilogue (bit-identical).
__global__ __launch_bounds__(256) void score_gemm_k(
    const short* __restrict__ Ah, const short* __restrict__ Al,   // qi_hi/lo [16384][128]
    const short* __restrict__ Bh, const short* __restrict__ Bl,   // ki_hi/lo [1024][128]
    const float* __restrict__ wproj, const int* __restrict__ ks,
    const int* __restrict__ ke, float* __restrict__ scores)
{
  __shared__ short Ahs[2][128 * 32];
  __shared__ short Als[2][128 * 32];
  __shared__ short Bhs[2][128 * 32];
  __shared__ short Bls[2][128 * 32];
  __shared__ float s_w[8][16];
  __shared__ int s_ks[8], s_ke[8];
  const int tid = threadIdx.x;
  const int bm = blockIdx.y * 128, bn = blockIdx.x * 128;
  const int wave = tid >> 6, lane = tid & 63;
  const int wm = (wave >> 1) * 64, wn = (wave & 1) * 64;
  const int sr = tid >> 2;
  const int scol = (tid & 3) * 8;
  const int m0 = lane & 15, koff = (lane >> 4) * 8;
  const int t0 = bm >> 4;   // first of this tile's 8 tokens
  if (tid < 128) s_w[tid >> 4][tid & 15] =
      wproj[(t0 + (tid >> 4)) * HI_ + (tid & 15)] * 0.022097086912079608f;
  if (tid < 8) { s_ks[tid] = ks[t0 + tid]; s_ke[tid] = ke[t0 + tid]; }
  f32x4 acc[4][4] = {};
  const short* gah = Ah + (long long)(bm + sr) * DI_ + scol;
  const short* gal = Al + (long long)(bm + sr) * DI_ + scol;
  const short* gbh = Bh + (long long)(bn + sr) * DI_ + scol;
  const short* gbl = Bl + (long long)(bn + sr) * DI_ + scol;
#define STAGE_S(buf, off) \
    GLL(gah + (off), Ahs[buf] + tid * 8); GLL(gah + (off) + 64 * DI_, Ahs[buf] + tid * 8 + 2048); \
    GLL(gal + (off), Als[buf] + tid * 8); GLL(gal + (off) + 64 * DI_, Als[buf] + tid * 8 + 2048); \
    GLL(gbh + (off), Bhs[buf] + tid * 8); GLL(gbh + (off) + 64 * DI_, Bhs[buf] + tid * 8 + 2048); \
    GLL(gbl + (off), Bls[buf] + tid * 8); GLL(gbl + (off) + 64 * DI_, Bls[buf] + tid * 8 + 2048);
  const int niter = DI_ >> 5;   // 4
  STAGE_S(0, 0);
  for (int it = 0; it < niter; ++it) {
    const int cur = it & 1;
    if (it + 1 < niter) {
      STAGE_S(cur ^ 1, (it + 1) * 32);
      asm volatile("s_waitcnt vmcnt(8)\ns_barrier" ::: "memory");
    } else {
      asm volatile("s_waitcnt vmcnt(0)\ns_barrier" ::: "memory");
    }
    bfrag_t afh[4], afl[4], bfh[4], bfl[4];
#pragma unroll
    for (int i = 0; i < 4; ++i) {
      afh[i] = *(const bfrag_t*)(Ahs[cur] + (wm + i * 16 + m0) * 32 + koff);
      afl[i] = *(const bfrag_t*)(Als[cur] + (wm + i * 16 + m0) * 32 + koff);
    }
#pragma unroll
    for (int j = 0; j < 4; ++j) {
      bfh[j] = *(const bfrag_t*)(Bhs[cur] + (wn + j * 16 + m0) * 32 + koff);
      bfl[j] = *(const bfrag_t*)(Bls[cur] + (wn + j * 16 + m0) * 32 + koff);
    }
#pragma unroll
    for (int i = 0; i < 4; ++i)
#pragma unroll
      for (int j = 0; j < 4; ++j)
        acc[i][j] = __builtin_amdgcn_mfma_f32_16x16x32_bf16(afh[i], bfh[j], acc[i][j], 0, 0, 0);
#pragma unroll
    for (int i = 0; i < 4; ++i)
#pragma unroll
      for (int j = 0; j < 4; ++j)
        acc[i][j] = __builtin_amdgcn_mfma_f32_16x16x32_bf16(afh[i], bfl[j], acc[i][j], 0, 0, 0);
#pragma unroll
    for (int i = 0; i < 4; ++i)
#pragma unroll
      for (int j = 0; j < 4; ++j)
        acc[i][j] = __builtin_amdgcn_mfma_f32_16x16x32_bf16(afl[i], bfh[j], acc[i][j], 0, 0, 0);
    asm volatile("s_barrier" ::: "memory");
  }
#undef STAGE_S
  const int cc = lane & 15, quad = lane >> 4;
#pragma unroll
  for (int i = 0; i < 4; ++i) {
    const int g = (wm >> 4) + i;          // token slot 0..7 within the tile
    const int tok = t0 + g;
    const int lo = s_ks[g], hi = s_ke[g];
#pragma unroll
    for (int j = 0; j < 4; ++j) {
      float sc = 0.f;
#pragma unroll
      for (int r = 0; r < 4; ++r)
        sc += fmaxf(acc[i][j][r], 0.f) * s_w[g][quad * 4 + r];
      sc += __shfl_xor(sc, 16);
      sc += __shfl_xor(sc, 32);
      if (quad == 0) {
        const int s = bn + wn + j * 16 + cc;
        scores[tok * T_ + s] = (s >= lo && s <= hi) ? sc : NEGF;
      }
    }
  }
}

// ================= casts / decompose =================
__global__ __launch_bounds__(256) void cast_bf16_k(const float* __restrict__ src,
                                                   __hip_bfloat16* __restrict__ dst, int n4) {
  int i = blockIdx.x * 256 + threadIdx.x;
  if (i >= n4) return;
  float4 v = ((const float4*)src)[i];
  union { ushort4 u; __hip_bfloat16 h[4]; } o;
  o.h[0] = __float2bfloat16(v.x); o.h[1] = __float2bfloat16(v.y);
  o.h[2] = __float2bfloat16(v.z); o.h[3] = __float2bfloat16(v.w);
  ((ushort4*)dst)[i] = o.u;
}

__global__ __launch_bounds__(256) void decomp_k(const float* __restrict__ src,
                                                __hip_bfloat16* __restrict__ hi,
                                                __hip_bfloat16* __restrict__ lo, int n4) {
  int i = blockIdx.x * 256 + threadIdx.x;
  if (i >= n4) return;
  float4 v = ((const float4*)src)[i];
  float f[4] = {v.x, v.y, v.z, v.w};
  union { ushort4 u; __hip_bfloat16 h[4]; } oh, ol;
#pragma unroll
  for (int j = 0; j < 4; ++j) {
    __hip_bfloat16 h = __float2bfloat16(f[j]);
    oh.h[j] = h;
    ol.h[j] = __float2bfloat16(f[j] - __bfloat162float(h));
  }
  ((ushort4*)hi)[i] = oh.u;
  ((ushort4*)lo)[i] = ol.u;
}

__global__ __launch_bounds__(256) void cast_pad_k(const float* __restrict__ src,
                                                  __hip_bfloat16* __restrict__ dst,
                                                  int N, int K4, int Npad) {
  int i = blockIdx.x * 256 + threadIdx.x;
  if (i >= Npad * K4) return;
  int r = i / K4;
  float4 v = make_float4(0.f, 0.f, 0.f, 0.f);
  if (r < N) v = ((const float4*)src)[i];
  union { ushort4 u; __hip_bfloat16 h[4]; } o;
  o.h[0] = __float2bfloat16(v.x); o.h[1] = __float2bfloat16(v.y);
  o.h[2] = __float2bfloat16(v.z); o.h[3] = __float2bfloat16(v.w);
  ((ushort4*)dst)[i] = o.u;
}

// w_kn transposed-cast via LDS 64x64 tile: dst[h][k][d] = w_kvb[(h*256+d)*512+k]
__global__ __launch_bounds__(256) void wkn_t_k(const float* __restrict__ wkvb,
                                               __hip_bfloat16* __restrict__ dst) {
  __shared__ float tile[64][65];
  const int h = blockIdx.z, k0 = blockIdx.y * 64, d0 = blockIdx.x * 64;
  const int c = threadIdx.x & 63, r0 = threadIdx.x >> 6;
#pragma unroll
  for (int rr = 0; rr < 16; ++rr) {
    int r = r0 + rr * 4;
    tile[r][c] = wkvb[((h * 256 + d0 + r) << 9) + k0 + c];  // coalesced (k fast)
  }
  __syncthreads();
#pragma unroll
  for (int rr = 0; rr < 16; ++rr) {
    int r = r0 + rr * 4;   // k-local
    dst[((h * 512 + k0 + r) << 7) + d0 + c] = __float2bfloat16(tile[c][r]); // coalesced (d fast)
  }
}

__global__ __launch_bounds__(256) void wv_cast_k(const float* __restrict__ wkvb,
                                                 __hip_bfloat16* __restrict__ dst) {
  int i = blockIdx.x * 256 + threadIdx.x;
  int k = i & 511, dv = (i >> 9) & 127, h = i >> 16;
  dst[i] = __float2bfloat16(wkvb[((h * 256 + 128 + dv) << 9) + k]);
}

// ================= RMSNorm in-place (fp32) =================
__global__ __launch_bounds__(256) void rms_inplace_k(float* x, const float* __restrict__ g,
                                                     int C) {
  int t = blockIdx.x, tid = threadIdx.x;
  float* row = x + (long long)t * C;
  float ss = 0.f;
  for (int i = tid; i < C; i += 256) { float v = row[i]; ss += v * v; }
  __shared__ float red[4];
  ss = wave_sum64(ss);
  if ((tid & 63) == 0) red[tid >> 6] = ss;
  __syncthreads();
  float sc = rsqrtf((red[0] + red[1] + red[2] + red[3]) / (float)C + 1e-6f);
  for (int i = tid; i < C; i += 256) row[i] = row[i] * sc * g[i];
}

// ================= skv build -> bf16; row T_ = 0 =================
__global__ __launch_bounds__(256) void skv_build_k(const float* __restrict__ ckv,
                                                   const float* __restrict__ g,
                                                   const float* __restrict__ cosb,
                                                   const float* __restrict__ sinb,
                                                   __hip_bfloat16* __restrict__ skv) {
  int t = blockIdx.x, tid = threadIdx.x;
  __hip_bfloat16* out = skv + (long long)t * 576;
  if (t == T_) { for (int i = tid; i < 576; i += 256) out[i] = __float2bfloat16(0.f); return; }
  const float* row = ckv + (long long)t * 576;
  float ss = 0.f;
  for (int i = tid; i < 512; i += 256) { float v = row[i]; ss += v * v; }
  __shared__ float red[4];
  ss = wave_sum64(ss);
  if ((tid & 63) == 0) red[tid >> 6] = ss;
  __syncthreads();
  float sc = rsqrtf((red[0] + red[1] + red[2] + red[3]) / 512.f + 1e-6f);
  for (int i = tid; i < 512; i += 256) out[i] = __float2bfloat16(row[i] * sc * g[i]);
  if (tid < 64) {
    int j = tid, j2 = tid & 31;
    float c = cosb[t * 64 + j], s = sinb[t * 64 + j];
    float a = row[512 + 2 * j2], b = row[512 + 2 * j2 + 1];
    out[512 + j] = __float2bfloat16((j < 32) ? (a * c - b * s) : (a * s + b * c));
  }
}

// ================= rope in-place on qi heads (fp32) =================
__global__ __launch_bounds__(64) void rope_qi_k(float* qi, const float* __restrict__ cosb,
                                                const float* __restrict__ sinb) {
  int b = blockIdx.x, t = b >> 4, j = threadIdx.x, j2 = j & 31;
  float* x = qi + (long long)b * DI_;
  float c = cosb[t * 64 + j], s = sinb[t * 64 + j];
  float a = x[2 * j2], bb = x[2 * j2 + 1];
  float o = (j < 32) ? (a * c - bb * s) : (a * s + bb * c);
  x[j] = o;
}

// ================= ki: LayerNorm then rope, in-place (fp32) =================
__global__ __launch_bounds__(128) void ki_ln_rope_k(float* kbuf, const float* __restrict__ w,
                                                    const float* __restrict__ bia,
                                                    const float* __restrict__ cosb,
                                                    const float* __restrict__ sinb) {
  int t = blockIdx.x, i = threadIdx.x;
  float* row = kbuf + (long long)t * DI_;
  float x = row[i];
  __shared__ float red[2];
  float s1 = wave_sum64(x);
  if ((i & 63) == 0) red[i >> 6] = s1;
  __syncthreads();
  float mean = (red[0] + red[1]) / 128.f;
  float d = x - mean;
  __syncthreads();
  float s2 = wave_sum64(d * d);
  if ((i & 63) == 0) red[i >> 6] = s2;
  __syncthreads();
  float var = (red[0] + red[1]) / 128.f;
  float y = d * rsqrtf(var + 1e-6f) * w[i] + bia[i];
  __shared__ float rowl[128];
  rowl[i] = y;
  __syncthreads();
  float outv = y;
  if (i < 64) {
    int j2 = i & 31;
    float c = cosb[t * 64 + i], s = sinb[t * 64 + i];
    float a = rowl[2 * j2], b = rowl[2 * j2 + 1];
    outv = (i < 32) ? (a * c - b * s) : (a * s + b * c);
  }
  row[i] = outv;
}

// ================= rope q_full tail (bf16 in) -> sq_bf[...,512:576] =================
__global__ __launch_bounds__(64) void rope_q_sq_k(const __hip_bfloat16* __restrict__ qfull,
                                                  const float* __restrict__ cosb,
                                                  const float* __restrict__ sinb,
                                                  __hip_bfloat16* __restrict__ sq) {
  int b = blockIdx.x, t = b >> 4, h = b & 15, j = threadIdx.x, j2 = j & 31;
  const __hip_bfloat16* x = qfull + (long long)t * 3072 + h * 192 + 128;
  float c = cosb[t * 64 + j], s = sinb[t * 64 + j];
  float a = __bfloat162float(x[2 * j2]), bb = __bfloat162float(x[2 * j2 + 1]);
  float o = (j < 32) ? (a * c - bb * s) : (a * s + bb * c);
  sq[((long long)t * H_ + h) * 576 + 512 + j] = __float2bfloat16(o);
}

// ================= w = hidden @ i_wproj.T (fp32) =================
__global__ __launch_bounds__(256) void wproj_k(const float* __restrict__ hidden,
                                               const float* __restrict__ wp,
                                               float* __restrict__ out) {
  int wave = threadIdx.x >> 6, lane = threadIdx.x & 63;
  int t = blockIdx.x * 4 + wave;
  const float4* x4 = (const float4*)(hidden + (long long)t * 2048);
  float acc[16] = {};
  for (int c = lane; c < 512; c += 64) {
    float4 xv = x4[c];
#pragma unroll
    for (int h = 0; h < 16; ++h) {
      float4 wv = ((const float4*)(wp + h * 2048))[c];
      acc[h] += xv.x * wv.x + xv.y * wv.y + xv.z * wv.z + xv.w * wv.w;
    }
  }
#pragma unroll
  for (int h = 0; h < 16; ++h) {
    float s = wave_sum64(acc[h]);
    if (lane == 0) out[t * 16 + h] = s;
  }
}

// ========== exact radix-select top-256 — keys in registers, ballot-aggregated atomics ======
__global__ __launch_bounds__(256) void topk_k(const float* __restrict__ scores,
                                              int* __restrict__ indices)
{
  __shared__ unsigned s_hist[256];
  __shared__ unsigned s_wsum[4];
  __shared__ unsigned s_binsel[2];
  __shared__ unsigned s_cnt;
  const int t = blockIdx.x, tid = threadIdx.x;
  const int wave = tid >> 6, lane = tid & 63;
  const int i0 = tid * 4;
  if (tid == 0) s_cnt = 0;

  float4 sv = ((const float4*)(scores + t * T_))[tid];
  float f[4] = {sv.x, sv.y, sv.z, sv.w};
  unsigned key[4];
#pragma unroll
  for (int j = 0; j < 4; ++j) {
    unsigned u = __float_as_uint(f[j]);
    key[j] = (u & 0x80000000u) ? ~u : (u | 0x80000000u);
  }

  unsigned prefix = 0, Gprev = 0;
  for (int lvl = 0; lvl < 4; ++lvl) {
    const int shift = 24 - 8 * lvl;
    s_hist[tid] = 0;
    __syncthreads();
#pragma unroll
    for (int j = 0; j < 4; ++j) {
      unsigned k = key[j];
      bool part = (lvl == 0) || ((k >> (shift + 8)) == prefix);
      unsigned bin = (k >> shift) & 255u;
      unsigned long long mask = __ballot(part);
#pragma unroll
      for (int b = 0; b < 8; ++b) {
        unsigned long long bal = __ballot((bin >> b) & 1u);
        mask &= ((bin >> b) & 1u) ? bal : ~bal;
      }
      if (part && lane == (__ffsll((long long)mask) - 1))
        atomicAdd(&s_hist[bin], (unsigned)__popcll(mask));
    }
    __syncthreads();
    unsigned h = s_hist[255 - tid];
    unsigned sc_ = h;
    for (int off = 1; off < 64; off <<= 1) {
      unsigned v = __shfl_up(sc_, off);
      if (lane >= off) sc_ += v;
    }
    if (lane == 63) s_wsum[wave] = sc_;
    __syncthreads();
    unsigned wo = 0;
    for (int w = 0; w < wave; ++w) wo += s_wsum[w];
    unsigned incl = sc_ + wo, excl = incl - h;
    unsigned Rn = 256 - Gprev;
    if (excl < Rn && Rn <= incl) { s_binsel[0] = 255 - (unsigned)tid; s_binsel[1] = excl; }
    __syncthreads();
    prefix = (prefix << 8) | s_binsel[0];
    Gprev += s_binsel[1];
  }
  const unsigned thr = prefix;
  const unsigned Rq = 256 - Gprev;
  const unsigned negfkey = ~__float_as_uint(NEGF);

  unsigned eqc = 0;
#pragma unroll
  for (int j = 0; j < 4; ++j) eqc += (key[j] == thr) ? 1u : 0u;
  unsigned esc = eqc;
  for (int off = 1; off < 64; off <<= 1) {
    unsigned v = __shfl_up(esc, off);
    if (lane >= off) esc += v;
  }
  if (lane == 63) s_wsum[wave] = esc;
  __syncthreads();
  unsigned eo = 0;
  for (int w = 0; w < wave; ++w) eo += s_wsum[w];
  unsigned rank = esc + eo - eqc;

#pragma unroll
  for (int j = 0; j < 4; ++j) {
    unsigned k = key[j];
    int outv = (k == negfkey) ? T_ : (i0 + j);
    bool gt = (k > thr);
    unsigned long long bal = __ballot(gt);
    if (bal) {
      int leader = __ffsll((long long)bal) - 1;
      unsigned base = 0;
      if (lane == leader) base = atomicAdd(&s_cnt, (unsigned)__popcll(bal));
      base = (unsigned)__shfl((int)base, leader);
      if (gt) {
        unsigned pre = (unsigned)__popcll(bal & ((1ull << lane) - 1ull));
        indices[t * TOPK_ + base + pre] = outv;
      }
    }
    if (!gt && k == thr) {
      if (rank < Rq) indices[t * TOPK_ + Gprev + rank] = outv;
      rank++;
    }
  }
}

// ========= MFMA gathered attention — 512 thr, 2 PV wave-groups, XOR-swizzled V-LDS =========
#define SP_LD 257
#define PB_LD 264
#define VT_LD 264
__global__ __launch_bounds__(512) void attn_k(
    const short* __restrict__ sq, const short* __restrict__ skv,
    const int* __restrict__ indices, __hip_bfloat16* __restrict__ attn_out)
{
  __shared__ int s_ind[TOPK_];
  __shared__ __align__(16) char s_un[2 * 64 * VT_LD * 2];  // 67584 B
  float* s_p  = (float*)s_un;                 // [H_][SP_LD] = 16448 B (QK..pack phase)
  short* s_pb = (short*)(s_un + 16448);       // [H_][PB_LD] =  8448 B (disjoint from s_p)
  short* s_vt = (short*)s_un;                 // [2][64][VT_LD] (PV phase)
  const int t = blockIdx.x, tid = threadIdx.x;
  const int wave = tid >> 6, lane = tid & 63;
  const int m0 = lane & 15, quad = lane >> 4;
  if (tid < TOPK_) s_ind[tid] = indices[t * TOPK_ + tid];
  __syncthreads();

  // ---- QK^T: each wave owns 32 KV rows ----
  {
    const int jb = wave * 32;
    int rows[2];
    const short* kvp[2];
#pragma unroll
    for (int j = 0; j < 2; ++j) {
      rows[j] = s_ind[jb + j * 16 + m0];
      kvp[j] = skv + rows[j] * 576 + quad * 8;
    }
    const short* qp = sq + ((long long)t * H_ + m0) * 576 + quad * 8;
    f32x4 qacc[2] = {};
    for (int ks = 0; ks < 18; ++ks) {
      const int k0 = ks * 32;
      bfrag_t aq = *(const bfrag_t*)(qp + k0);
#pragma unroll
      for (int j = 0; j < 2; ++j) {
        bfrag_t bq = *(const bfrag_t*)(kvp[j] + k0);
        qacc[j] = __builtin_amdgcn_mfma_f32_16x16x32_bf16(aq, bq, qacc[j], 0, 0, 0);
      }
    }
    const float scale = 0.07216878364870322f;
#pragma unroll
    for (int j = 0; j < 2; ++j) {
      int key = jb + j * 16 + m0;
      bool msk = (rows[j] == T_);
#pragma unroll
      for (int r = 0; r < 4; ++r)
        s_p[(quad * 4 + r) * SP_LD + key] = msk ? NEGF : qacc[j][r] * scale;
    }
  }
  __syncthreads();

  // ---- softmax (2 heads per wave) ----
  for (int h = wave * 2; h < wave * 2 + 2; ++h) {
    float* ph = s_p + h * SP_LD;
    float m = -3.4e38f;
    for (int j = lane; j < TOPK_; j += 64) m = fmaxf(m, ph[j]);
#pragma unroll
    for (int off = 32; off; off >>= 1) m = fmaxf(m, __shfl_xor(m, off));
    float sum = 0.f;
    for (int j = lane; j < TOPK_; j += 64) {
      float e = __expf(ph[j] - m);
      ph[j] = e; sum += e;
    }
    sum = wave_sum64(sum);
    float inv = 1.f / sum;
    for (int j = lane; j < TOPK_; j += 64) ph[j] *= inv;
  }
  __syncthreads();

  // ---- pack P -> bf16 (s_pb disjoint from s_p) ----
  {
    const int col = tid & 255, h0 = tid >> 8;
#pragma unroll
    for (int h = 0; h < 8; ++h) {
      const int hh = h0 + h * 2;
      s_pb[hh * PB_LD + col] =
          (short)__bfloat16_as_ushort(__float2bfloat16(s_p[hh * SP_LD + col]));
    }
  }
  __syncthreads();

  bfrag_t apf[8];
#pragma unroll
  for (int kk = 0; kk < 8; ++kk)
    apf[kk] = *(const bfrag_t*)(s_pb + m0 * PB_LD + kk * 32 + quad * 8);

  // ---- PV: group = wave>>2 handles c in [grp*4, grp*4+4) with its own s_vt ----
  const int grp = wave >> 2, gw = wave & 3;
  short* svt = s_vt + grp * (64 * VT_LD);
  const int r8 = (tid >> 3) & 31;   // row slot within 256-thread group
  const int bb = tid & 7;           // 16B chunk within the 128B slab

  for (int cc = 0; cc < 4; ++cc) {
    const int c = grp * 4 + cc;
    __syncthreads();   // apf reads (first iter) / prev MFMA reads done; safe to overwrite svt
#pragma unroll
    for (int rep = 0; rep < 8; ++rep) {
      const int kv = r8 + 32 * rep;
      const int row = s_ind[kv];
      bfrag_t v = *(const bfrag_t*)(skv + (long long)row * 576 + c * 64 + bb * 8);
      const int colx = kv ^ (bb << 3);
#pragma unroll
      for (int j = 0; j < 8; ++j)
        svt[(bb * 8 + j) * VT_LD + colx] = v[j];
    }
    __syncthreads();
    const int d = gw * 16 + m0;
    const short* vrow = svt + d * VT_LD;
    const int sx = (d >> 3) << 3;
    f32x4 oacc = {0.f, 0.f, 0.f, 0.f};
#pragma unroll
    for (int kk = 0; kk < 8; ++kk) {
      bfrag_t bv = *(const bfrag_t*)(vrow + ((kk * 32 + quad * 8) ^ sx));
      oacc = __builtin_amdgcn_mfma_f32_16x16x32_bf16(apf[kk], bv, oacc, 0, 0, 0);
    }
    const int col = c * 64 + d;
#pragma unroll
    for (int r = 0; r < 4; ++r)
      attn_out[((long long)t * H_ + quad * 4 + r) * 512 + col] = __float2bfloat16(oacc[r]);
  }
}

extern "C" void kernel_launch(void* const* d_in, const int* in_sizes, int n_in,
                              void* d_out, int out_size, void* d_ws, size_t ws_size,
                              hipStream_t stream) {
  const float* hidden  = (const float*)d_in[0];
  const float* cosb    = (const float*)d_in[1];
  const float* sinb    = (const float*)d_in[2];
  const int*   ks      = (const int*)d_in[3];
  const int*   ke      = (const int*)d_in[4];
  const float* w_qa    = (const float*)d_in[5];
  const float* g_qa    = (const float*)d_in[6];
  const float* w_qb    = (const float*)d_in[7];
  const float* w_kva   = (const float*)d_in[8];
  const float* g_kva   = (const float*)d_in[9];
  const float* w_kvb   = (const float*)d_in[10];
  const float* w_o     = (const float*)d_in[11];
  const float* i_wqb   = (const float*)d_in[12];
  const float* i_wk    = (const float*)d_in[13];
  const float* i_ln_w  = (const float*)d_in[14];
  const float* i_ln_b  = (const float*)d_in[15];
  const float* i_wproj = (const float*)d_in[16];
  float* out = (float*)d_out;
  (void)in_sizes; (void)n_in; (void)out_size; (void)ws_size;

  // ---- workspace (bytes), lifetime-overlapped (layout verified R6) ----
  char* ws = (char*)d_ws;
  __hip_bfloat16* hid_hi  = (__hip_bfloat16*)(ws + 0);
  __hip_bfloat16* hid_lo  = (__hip_bfloat16*)(ws + 4194304);
  float*          q_lat   = (float*)(ws + 8388608);
  __hip_bfloat16* qi_hi   = (__hip_bfloat16*)(ws + 8388608);    // over dead q_lat
  __hip_bfloat16* qlat_hi = (__hip_bfloat16*)(ws + 14680064);
  __hip_bfloat16* qlat_lo = (__hip_bfloat16*)(ws + 17825792);
  float*          qi      = (float*)(ws + 20971520);
  float*          scoresb = (float*)(ws + 20971520);            // over dead qi (post-decomp)
  float*          kib     = (float*)(ws + 29360128);
  float*          wbuf    = (float*)(ws + 29884416);
  float*          ckv     = (float*)(ws + 29949952);
  __hip_bfloat16* qi_lo   = (__hip_bfloat16*)(ws + 29949952);   // over dead ckv
  __hip_bfloat16* ki_hi   = (__hip_bfloat16*)(ws + 34144256);
  __hip_bfloat16* ki_lo   = (__hip_bfloat16*)(ws + 34406400);
  __hip_bfloat16* sq_bf   = (__hip_bfloat16*)(ws + 0);
  __hip_bfloat16* o_bf    = (__hip_bfloat16*)(ws + 0);
  __hip_bfloat16* W       = (__hip_bfloat16*)(ws + 37748736);
  __hip_bfloat16* skv_bf  = (__hip_bfloat16*)(ws + 47185920);
  int*            idxb    = (int*)(ws + 48366720);
  __hip_bfloat16* E       = (__hip_bfloat16*)(ws + 49415296);

  dim3 blk(256);
  const short* Ws = (const short*)W;
  const short* Es = (const short*)E;

  decomp_k<<<2048, blk, 0, stream>>>(hidden, hid_hi, hid_lo, 524288);

  // ---- q_lat = hidden @ w_qa^T (split-K=4: 384 blocks) ----
  decomp_k<<<3072, blk, 0, stream>>>(w_qa, W, E, 786432);
  zero_k<<<1536, blk, 0, stream>>>((float4*)q_lat, 393216);
  gemm3_k<<<dim3(12, 8, 4), blk, 0, stream>>>(
      (const short*)hid_hi, (const short*)hid_lo, HID_, Ws, Es, HID_, q_lat, LQ_, LQ_, 512);
  rms_inplace_k<<<T_, blk, 0, stream>>>(q_lat, g_qa, LQ_);

  // ---- ckv = hidden @ w_kva^T (split-K=4: 160 blocks) ----
  cast_pad_k<<<1280, blk, 0, stream>>>(w_kva, W, 576, 512, 640);
  zero_k<<<576, blk, 0, stream>>>((float4*)ckv, 147456);
  gemm_bfs_k<<<dim3(5, 8, 4), blk, 0, stream>>>(
      (const short*)hid_hi, HID_, Ws, HID_, ckv, 576, 576, 512);
  skv_build_k<<<T_ + 1, blk, 0, stream>>>(ckv, g_kva, cosb, sinb, skv_bf);

  decomp_k<<<1536, blk, 0, stream>>>(q_lat, qlat_hi, qlat_lo, 393216);

  // ---- qi = q_lat @ i_wqb^T (split-K=4: 512 blocks) ----
  decomp_k<<<3072, blk, 0, stream>>>(i_wqb, W, E, 786432);
  zero_k<<<2048, blk, 0, stream>>>((float4*)qi, 524288);
  gemm3_k<<<dim3(16, 8, 4), blk, 0, stream>>>(
      (const short*)qlat_hi, (const short*)qlat_lo, LQ_, Ws, Es, LQ_, qi, HI_ * DI_, HI_ * DI_, 384);
  rope_qi_k<<<T_ * HI_, dim3(64), 0, stream>>>(qi, cosb, sinb);
  decomp_k<<<2048, blk, 0, stream>>>(qi, qi_hi, qi_lo, 524288);

  // ---- kib = hidden @ i_wk^T (split-K=16: 128 blocks) ----
  decomp_k<<<256, blk, 0, stream>>>(i_wk, W, E, 65536);
  zero_k<<<128, blk, 0, stream>>>((float4*)kib, 32768);
  gemm3_k<<<dim3(1, 8, 16), blk, 0, stream>>>(
      (const short*)hid_hi, (const short*)hid_lo, HID_, Ws, Es, HID_, kib, DI_, DI_, 128);
  ki_ln_rope_k<<<T_, dim3(128), 0, stream>>>(kib, i_ln_w, i_ln_b, cosb, sinb);
  decomp_k<<<128, blk, 0, stream>>>(kib, ki_hi, ki_lo, 32768);

  wproj_k<<<256, blk, 0, stream>>>(hidden, i_wproj, wbuf);

  // ---- indexer: GEMM-shaped scores (GLL pipeline) then register-key radix select ----
  score_gemm_k<<<dim3(8, 128), blk, 0, stream>>>(
      (const short*)qi_hi, (const short*)qi_lo, (const short*)ki_hi, (const short*)ki_lo,
      wbuf, ks, ke, scoresb);
  topk_k<<<T_, blk, 0, stream>>>(scoresb, idxb);

  cast_bf16_k<<<4608, blk, 0, stream>>>(w_qb, W, 1179648);
  gemm_bf_k<__hip_bfloat16><<<dim3(24, 8, 1), blk, 0, stream>>>(
      (const short*)qlat_hi, LQ_, 0, Ws, LQ_, 0, (__hip_bfloat16*)E, H_ * DQ_, 0, H_ * DQ_, LQ_);
  rope_q_sq_k<<<T_ * H_, dim3(64), 0, stream>>>(E, cosb, sinb, sq_bf);

  wkn_t_k<<<dim3(2, 8, 16), blk, 0, stream>>>(w_kvb, W);
  gemm_bf_k<__hip_bfloat16><<<dim3(4, 8, 16), blk, 0, stream>>>(
      Es, H_ * DQ_, 192, Ws, DI_, 65536, sq_bf, H_ * 576, 576, LKV_, DN_);

  attn_k<<<T_, dim3(512), 0, stream>>>((const short*)sq_bf, (const short*)skv_bf, idxb, E);

  wv_cast_k<<<4096, blk, 0, stream>>>(w_kvb, W);
  gemm_bf_k<__hip_bfloat16><<<dim3(1, 8, 16), blk, 0, stream>>>(
      Es, H_ * LKV_, 512, Ws, LKV_, 65536, o_bf, H_ * DV_, 128, DV_, LKV_);

  // ---- out = o_bf @ w_o^T (split-K=4: 512 blocks) ----
  cast_bf16_k<<<4096, blk, 0, stream>>>(w_o, W, 1048576);
  zero_k<<<2048, blk, 0, stream>>>((float4*)out, 524288);
  gemm_bfs_k<<<dim3(16, 8, 4), blk, 0, stream>>>(
      (const short*)o_bf, H_ * DV_, Ws, H_ * DV_, out, HID_, HID_, 512);
}

// Round 9
// 531.282 us; speedup vs baseline: 1.1252x; 1.0214x over previous
//
#include <hip/hip_runtime.h>
#include <hip/hip_bf16.h>
#include <cmath>

#define T_ 1024
#define HID_ 2048
#define H_ 16
#define LQ_ 1536
#define LKV_ 512
#define DR_ 64
#define DN_ 128
#define DQ_ 192
#define DV_ 128
#define HI_ 16
#define DI_ 128
#define TOPK_ 256
#define NEGF (-1e30f)

typedef short bfrag_t __attribute__((ext_vector_type(8)));   // 8 bf16 = 4 VGPRs
typedef float f32x4 __attribute__((ext_vector_type(4)));

__device__ __forceinline__ float wave_sum64(float v) {
#pragma unroll
  for (int off = 32; off; off >>= 1) v += __shfl_xor(v, off);
  return v;
}

#define GLL(g, l) __builtin_amdgcn_global_load_lds((const __attribute__((address_space(1))) void*)(g), \
                                     (__attribute__((address_space(3))) void*)(l), 16, 0, 0)

// ================= zero fill (for split-K atomic accumulation) =================
__global__ __launch_bounds__(256) void zero_k(float4* __restrict__ p, int n4) {
  int i = blockIdx.x * 256 + threadIdx.x;
  if (i < n4) p[i] = make_float4(0.f, 0.f, 0.f, 0.f);
}

// ================= bf16 MFMA GEMM: C = A @ B^T — double-buffered, raw-barrier pipeline ====
template<typename CT>
__global__ __launch_bounds__(256) void gemm_bf_k(
    const short* __restrict__ A, int lda, long long sA,
    const short* __restrict__ B, int ldb, long long sB,
    CT* __restrict__ C, int ldc, long long sC,
    int Nout, int K)
{
  __shared__ short As[2][128 * 32];
  __shared__ short Bs[2][128 * 32];
  A += (long long)blockIdx.z * sA;
  B += (long long)blockIdx.z * sB;
  C += (long long)blockIdx.z * sC;
  const int tid = threadIdx.x;
  const int bm = blockIdx.y * 128, bn = blockIdx.x * 128;
  const int wave = tid >> 6, lane = tid & 63;
  const int wm = (wave >> 1) * 64, wn = (wave & 1) * 64;
  const int sr = tid >> 2;
  const int scol = (tid & 3) * 8;
  const int m0 = lane & 15, koff = (lane >> 4) * 8;
  f32x4 acc[4][4] = {};
  const short* ga = A + (long long)(bm + sr) * lda + scol;
  const short* gb = B + (long long)(bn + sr) * ldb + scol;
#define STAGE_BF(buf, off) \
    GLL(ga + (off), As[buf] + tid * 8); GLL(ga + (off) + 64 * lda, As[buf] + tid * 8 + 2048); \
    GLL(gb + (off), Bs[buf] + tid * 8); GLL(gb + (off) + 64 * ldb, Bs[buf] + tid * 8 + 2048);
  const int niter = K >> 5;
  STAGE_BF(0, 0);
  for (int it = 0; it < niter; ++it) {
    const int cur = it & 1;
    if (it + 1 < niter) {
      STAGE_BF(cur ^ 1, (it + 1) * 32);
      asm volatile("s_waitcnt vmcnt(4)\ns_barrier" ::: "memory");
    } else {
      asm volatile("s_waitcnt vmcnt(0)\ns_barrier" ::: "memory");
    }
    bfrag_t af[4], bfv[4];
#pragma unroll
    for (int i = 0; i < 4; ++i)
      af[i] = *(const bfrag_t*)(As[cur] + (wm + i * 16 + m0) * 32 + koff);
#pragma unroll
    for (int j = 0; j < 4; ++j)
      bfv[j] = *(const bfrag_t*)(Bs[cur] + (wn + j * 16 + m0) * 32 + koff);
#pragma unroll
    for (int i = 0; i < 4; ++i)
#pragma unroll
      for (int j = 0; j < 4; ++j)
        acc[i][j] = __builtin_amdgcn_mfma_f32_16x16x32_bf16(af[i], bfv[j], acc[i][j], 0, 0, 0);
    asm volatile("s_barrier" ::: "memory");
  }
#undef STAGE_BF
  const int cr = (lane >> 4) * 4, cc = lane & 15;
#pragma unroll
  for (int i = 0; i < 4; ++i) {
    int row = bm + wm + i * 16 + cr;
#pragma unroll
    for (int j = 0; j < 4; ++j) {
      int col = bn + wn + j * 16 + cc;
      if (col < Nout) {
#pragma unroll
        for (int r = 0; r < 4; ++r)
          C[(long long)(row + r) * ldc + col] = (CT)(acc[i][j][r]);
      }
    }
  }
}

// ====== bf16 GEMM, fp32 out, split-K over blockIdx.z with atomic accumulate ======
__global__ __launch_bounds__(256) void gemm_bfs_k(
    const short* __restrict__ A, int lda,
    const short* __restrict__ B, int ldb,
    float* __restrict__ C, int ldc, int Nout, int K)
{
  __shared__ short As[2][128 * 32];
  __shared__ short Bs[2][128 * 32];
  const long long kbase = (long long)blockIdx.z * K;
  const int tid = threadIdx.x;
  const int bm = blockIdx.y * 128, bn = blockIdx.x * 128;
  const int wave = tid >> 6, lane = tid & 63;
  const int wm = (wave >> 1) * 64, wn = (wave & 1) * 64;
  const int sr = tid >> 2;
  const int scol = (tid & 3) * 8;
  const int m0 = lane & 15, koff = (lane >> 4) * 8;
  f32x4 acc[4][4] = {};
  const short* ga = A + (long long)(bm + sr) * lda + kbase + scol;
  const short* gb = B + (long long)(bn + sr) * ldb + kbase + scol;
#define STAGE_BS(buf, off) \
    GLL(ga + (off), As[buf] + tid * 8); GLL(ga + (off) + 64 * lda, As[buf] + tid * 8 + 2048); \
    GLL(gb + (off), Bs[buf] + tid * 8); GLL(gb + (off) + 64 * ldb, Bs[buf] + tid * 8 + 2048);
  const int niter = K >> 5;
  STAGE_BS(0, 0);
  for (int it = 0; it < niter; ++it) {
    const int cur = it & 1;
    if (it + 1 < niter) {
      STAGE_BS(cur ^ 1, (it + 1) * 32);
      asm volatile("s_waitcnt vmcnt(4)\ns_barrier" ::: "memory");
    } else {
      asm volatile("s_waitcnt vmcnt(0)\ns_barrier" ::: "memory");
    }
    bfrag_t af[4], bfv[4];
#pragma unroll
    for (int i = 0; i < 4; ++i)
      af[i] = *(const bfrag_t*)(As[cur] + (wm + i * 16 + m0) * 32 + koff);
#pragma unroll
    for (int j = 0; j < 4; ++j)
      bfv[j] = *(const bfrag_t*)(Bs[cur] + (wn + j * 16 + m0) * 32 + koff);
#pragma unroll
    for (int i = 0; i < 4; ++i)
#pragma unroll
      for (int j = 0; j < 4; ++j)
        acc[i][j] = __builtin_amdgcn_mfma_f32_16x16x32_bf16(af[i], bfv[j], acc[i][j], 0, 0, 0);
    asm volatile("s_barrier" ::: "memory");
  }
#undef STAGE_BS
  const int cr = (lane >> 4) * 4, cc = lane & 15;
#pragma unroll
  for (int i = 0; i < 4; ++i) {
    int row = bm + wm + i * 16 + cr;
#pragma unroll
    for (int j = 0; j < 4; ++j) {
      int col = bn + wn + j * 16 + cc;
      if (col < Nout) {
#pragma unroll
        for (int r = 0; r < 4; ++r)
          atomicAdd(&C[(long long)(row + r) * ldc + col], acc[i][j][r]);
      }
    }
  }
}

// ====== bf16x3 split GEMM (fp32-accurate) — double-buffered, split-K capable ======
__global__ __launch_bounds__(256) void gemm3_k(
    const short* __restrict__ Ah, const short* __restrict__ Al, int lda,
    const short* __restrict__ Bh, const short* __restrict__ Bl, int ldb,
    float* __restrict__ C, int ldc, int Nout, int K)
{
  __shared__ short Ahs[2][128 * 32];
  __shared__ short Als[2][128 * 32];
  __shared__ short Bhs[2][128 * 32];
  __shared__ short Bls[2][128 * 32];
  const long long kbase = (long long)blockIdx.z * K;
  const int tid = threadIdx.x;
  const int bm = blockIdx.y * 128, bn = blockIdx.x * 128;
  const int wave = tid >> 6, lane = tid & 63;
  const int wm = (wave >> 1) * 64, wn = (wave & 1) * 64;
  const int sr = tid >> 2;
  const int scol = (tid & 3) * 8;
  const int m0 = lane & 15, koff = (lane >> 4) * 8;
  f32x4 acc[4][4] = {};
  const short* gah = Ah + (long long)(bm + sr) * lda + kbase + scol;
  const short* gal = Al + (long long)(bm + sr) * lda + kbase + scol;
  const short* gbh = Bh + (long long)(bn + sr) * ldb + kbase + scol;
  const short* gbl = Bl + (long long)(bn + sr) * ldb + kbase + scol;
#define STAGE_3(buf, off) \
    GLL(gah + (off), Ahs[buf] + tid * 8); GLL(gah + (off) + 64 * lda, Ahs[buf] + tid * 8 + 2048); \
    GLL(gal + (off), Als[buf] + tid * 8); GLL(gal + (off) + 64 * lda, Als[buf] + tid * 8 + 2048); \
    GLL(gbh + (off), Bhs[buf] + tid * 8); GLL(gbh + (off) + 64 * ldb, Bhs[buf] + tid * 8 + 2048); \
    GLL(gbl + (off), Bls[buf] + tid * 8); GLL(gbl + (off) + 64 * ldb, Bls[buf] + tid * 8 + 2048);
  const int niter = K >> 5;
  STAGE_3(0, 0);
  for (int it = 0; it < niter; ++it) {
    const int cur = it & 1;
    if (it + 1 < niter) {
      STAGE_3(cur ^ 1, (it + 1) * 32);
      asm volatile("s_waitcnt vmcnt(8)\ns_barrier" ::: "memory");
    } else {
      asm volatile("s_waitcnt vmcnt(0)\ns_barrier" ::: "memory");
    }
    bfrag_t afh[4], afl[4], bfh[4], bfl[4];
#pragma unroll
    for (int i = 0; i < 4; ++i) {
      afh[i] = *(const bfrag_t*)(Ahs[cur] + (wm + i * 16 + m0) * 32 + koff);
      afl[i] = *(const bfrag_t*)(Als[cur] + (wm + i * 16 + m0) * 32 + koff);
    }
#pragma unroll
    for (int j = 0; j < 4; ++j) {
      bfh[j] = *(const bfrag_t*)(Bhs[cur] + (wn + j * 16 + m0) * 32 + koff);
      bfl[j] = *(const bfrag_t*)(Bls[cur] + (wn + j * 16 + m0) * 32 + koff);
    }
    // term-grouped: no back-to-back MFMAs on the same accumulator (per-acc fp32
    // add order unchanged: hh, hl, lh within each K-iter -> bit-identical)
#pragma unroll
    for (int i = 0; i < 4; ++i)
#pragma unroll
      for (int j = 0; j < 4; ++j)
        acc[i][j] = __builtin_amdgcn_mfma_f32_16x16x32_bf16(afh[i], bfh[j], acc[i][j], 0, 0, 0);
#pragma unroll
    for (int i = 0; i < 4; ++i)
#pragma unroll
      for (int j = 0; j < 4; ++j)
        acc[i][j] = __builtin_amdgcn_mfma_f32_16x16x32_bf16(afh[i], bfl[j], acc[i][j], 0, 0, 0);
#pragma unroll
    for (int i = 0; i < 4; ++i)
#pragma unroll
      for (int j = 0; j < 4; ++j)
        acc[i][j] = __builtin_amdgcn_mfma_f32_16x16x32_bf16(afl[i], bfh[j], acc[i][j], 0, 0, 0);
    asm volatile("s_barrier" ::: "memory");
  }
#undef STAGE_3
  const int cr = (lane >> 4) * 4, cc = lane & 15;
  const bool spl = (gridDim.z > 1);
#pragma unroll
  for (int i = 0; i < 4; ++i) {
    int row = bm + wm + i * 16 + cr;
#pragma unroll
    for (int j = 0; j < 4; ++j) {
      int col = bn + wn + j * 16 + cc;
      if (col < Nout) {
#pragma unroll
        for (int r = 0; r < 4; ++r) {
          if (spl) atomicAdd(&C[(long long)(row + r) * ldc + col], acc[i][j][r]);
          else     C[(long long)(row + r) * ldc + col] = acc[i][j][r];
        }
      }
    }
  }
}

// ====== indexer scores as a GEMM: logits = qi @ ki^T (bf16x3, M=16384 N=1024 K=128) ======
__global__ __launch_bounds__(256) void score_gemm_k(
    const short* __restrict__ Ah, const short* __restrict__ Al,   // qi_hi/lo [16384][128]
    const short* __restrict__ Bh, const short* __restrict__ Bl,   // ki_hi/lo [1024][128]
    const float* __restrict__ wproj, const int* __restrict__ ks,
    const int* __restrict__ ke, float* __restrict__ scores)
{
  __shared__ short Ahs[2][128 * 32];
  __shared__ short Als[2][128 * 32];
  __shared__ short Bhs[2][128 * 32];
  __shared__ short Bls[2][128 * 32];
  __shared__ float s_w[8][16];
  __shared__ int s_ks[8], s_ke[8];
  const int tid = threadIdx.x;
  const int bm = blockIdx.y * 128, bn = blockIdx.x * 128;
  const int wave = tid >> 6, lane = tid & 63;
  const int wm = (wave >> 1) * 64, wn = (wave & 1) * 64;
  const int sr = tid >> 2;
  const int scol = (tid & 3) * 8;
  const int m0 = lane & 15, koff = (lane >> 4) * 8;
  const int t0 = bm >> 4;   // first of this tile's 8 tokens
  if (tid < 128) s_w[tid >> 4][tid & 15] =
      wproj[(t0 + (tid >> 4)) * HI_ + (tid & 15)] * 0.022097086912079608f;
  if (tid < 8) { s_ks[tid] = ks[t0 + tid]; s_ke[tid] = ke[t0 + tid]; }
  f32x4 acc[4][4] = {};
  const short* gah = Ah + (long long)(bm + sr) * DI_ + scol;
  const short* gal = Al + (long long)(bm + sr) * DI_ + scol;
  const short* gbh = Bh + (long long)(bn + sr) * DI_ + scol;
  const short* gbl = Bl + (long long)(bn + sr) * DI_ + scol;
#define STAGE_S(buf, off) \
    GLL(gah + (off), Ahs[buf] + tid * 8); GLL(gah + (off) + 64 * DI_, Ahs[buf] + tid * 8 + 2048); \
    GLL(gal + (off), Als[buf] + tid * 8); GLL(gal + (off) + 64 * DI_, Als[buf] + tid * 8 + 2048); \
    GLL(gbh + (off), Bhs[buf] + tid * 8); GLL(gbh + (off) + 64 * DI_, Bhs[buf] + tid * 8 + 2048); \
    GLL(gbl + (off), Bls[buf] + tid * 8); GLL(gbl + (off) + 64 * DI_, Bls[buf] + tid * 8 + 2048);
  const int niter = DI_ >> 5;   // 4
  STAGE_S(0, 0);
  for (int it = 0; it < niter; ++it) {
    const int cur = it & 1;
    if (it + 1 < niter) {
      STAGE_S(cur ^ 1, (it + 1) * 32);
      asm volatile("s_waitcnt vmcnt(8)\ns_barrier" ::: "memory");
    } else {
      asm volatile("s_waitcnt vmcnt(0)\ns_barrier" ::: "memory");
    }
    bfrag_t afh[4], afl[4], bfh[4], bfl[4];
#pragma unroll
    for (int i = 0; i < 4; ++i) {
      afh[i] = *(const bfrag_t*)(Ahs[cur] + (wm + i * 16 + m0) * 32 + koff);
      afl[i] = *(const bfrag_t*)(Als[cur] + (wm + i * 16 + m0) * 32 + koff);
    }
#pragma unroll
    for (int j = 0; j < 4; ++j) {
      bfh[j] = *(const bfrag_t*)(Bhs[cur] + (wn + j * 16 + m0) * 32 + koff);
      bfl[j] = *(const bfrag_t*)(Bls[cur] + (wn + j * 16 + m0) * 32 + koff);
    }
#pragma unroll
    for (int i = 0; i < 4; ++i)
#pragma unroll
      for (int j = 0; j < 4; ++j)
        acc[i][j] = __builtin_amdgcn_mfma_f32_16x16x32_bf16(afh[i], bfh[j], acc[i][j], 0, 0, 0);
#pragma unroll
    for (int i = 0; i < 4; ++i)
#pragma unroll
      for (int j = 0; j < 4; ++j)
        acc[i][j] = __builtin_amdgcn_mfma_f32_16x16x32_bf16(afh[i], bfl[j], acc[i][j], 0, 0, 0);
#pragma unroll
    for (int i = 0; i < 4; ++i)
#pragma unroll
      for (int j = 0; j < 4; ++j)
        acc[i][j] = __builtin_amdgcn_mfma_f32_16x16x32_bf16(afl[i], bfh[j], acc[i][j], 0, 0, 0);
    asm volatile("s_barrier" ::: "memory");
  }
#undef STAGE_S
  const int cc = lane & 15, quad = lane >> 4;
#pragma unroll
  for (int i = 0; i < 4; ++i) {
    const int g = (wm >> 4) + i;          // token slot 0..7 within the tile
    const int tok = t0 + g;
    const int lo = s_ks[g], hi = s_ke[g];
#pragma unroll
    for (int j = 0; j < 4; ++j) {
      float sc = 0.f;
#pragma unroll
      for (int r = 0; r < 4; ++r)
        sc += fmaxf(acc[i][j][r], 0.f) * s_w[g][quad * 4 + r];
      sc += __shfl_xor(sc, 16);
      sc += __shfl_xor(sc, 32);
      if (quad == 0) {
        const int s = bn + wn + j * 16 + cc;
        scores[tok * T_ + s] = (s >= lo && s <= hi) ? sc : NEGF;
      }
    }
  }
}

// ================= casts / decompose =================
__global__ __launch_bounds__(256) void cast_bf16_k(const float* __restrict__ src,
                                                   __hip_bfloat16* __restrict__ dst, int n4) {
  int i = blockIdx.x * 256 + threadIdx.x;
  if (i >= n4) return;
  float4 v = ((const float4*)src)[i];
  union { ushort4 u; __hip_bfloat16 h[4]; } o;
  o.h[0] = __float2bfloat16(v.x); o.h[1] = __float2bfloat16(v.y);
  o.h[2] = __float2bfloat16(v.z); o.h[3] = __float2bfloat16(v.w);
  ((ushort4*)dst)[i] = o.u;
}

__global__ __launch_bounds__(256) void decomp_k(const float* __restrict__ src,
                                                __hip_bfloat16* __restrict__ hi,
                                                __hip_bfloat16* __restrict__ lo, int n4) {
  int i = blockIdx.x * 256 + threadIdx.x;
  if (i >= n4) return;
  float4 v = ((const float4*)src)[i];
  float f[4] = {v.x, v.y, v.z, v.w};
  union { ushort4 u; __hip_bfloat16 h[4]; } oh, ol;
#pragma unroll
  for (int j = 0; j < 4; ++j) {
    __hip_bfloat16 h = __float2bfloat16(f[j]);
    oh.h[j] = h;
    ol.h[j] = __float2bfloat16(f[j] - __bfloat162float(h));
  }
  ((ushort4*)hi)[i] = oh.u;
  ((ushort4*)lo)[i] = ol.u;
}

__global__ __launch_bounds__(256) void cast_pad_k(const float* __restrict__ src,
                                                  __hip_bfloat16* __restrict__ dst,
                                                  int N, int K4, int Npad) {
  int i = blockIdx.x * 256 + threadIdx.x;
  if (i >= Npad * K4) return;
  int r = i / K4;
  float4 v = make_float4(0.f, 0.f, 0.f, 0.f);
  if (r < N) v = ((const float4*)src)[i];
  union { ushort4 u; __hip_bfloat16 h[4]; } o;
  o.h[0] = __float2bfloat16(v.x); o.h[1] = __float2bfloat16(v.y);
  o.h[2] = __float2bfloat16(v.z); o.h[3] = __float2bfloat16(v.w);
  ((ushort4*)dst)[i] = o.u;
}

// w_kn transposed-cast via LDS 64x64 tile: dst[h][k][d] = w_kvb[(h*256+d)*512+k]
__global__ __launch_bounds__(256) void wkn_t_k(const float* __restrict__ wkvb,
                                               __hip_bfloat16* __restrict__ dst) {
  __shared__ float tile[64][65];
  const int h = blockIdx.z, k0 = blockIdx.y * 64, d0 = blockIdx.x * 64;
  const int c = threadIdx.x & 63, r0 = threadIdx.x >> 6;
#pragma unroll
  for (int rr = 0; rr < 16; ++rr) {
    int r = r0 + rr * 4;
    tile[r][c] = wkvb[((h * 256 + d0 + r) << 9) + k0 + c];  // coalesced (k fast)
  }
  __syncthreads();
#pragma unroll
  for (int rr = 0; rr < 16; ++rr) {
    int r = r0 + rr * 4;   // k-local
    dst[((h * 512 + k0 + r) << 7) + d0 + c] = __float2bfloat16(tile[c][r]); // coalesced (d fast)
  }
}

__global__ __launch_bounds__(256) void wv_cast_k(const float* __restrict__ wkvb,
                                                 __hip_bfloat16* __restrict__ dst) {
  int i = blockIdx.x * 256 + threadIdx.x;
  int k = i & 511, dv = (i >> 9) & 127, h = i >> 16;
  dst[i] = __float2bfloat16(wkvb[((h * 256 + 128 + dv) << 9) + k]);
}

// ================= RMSNorm in-place (fp32) =================
__global__ __launch_bounds__(256) void rms_inplace_k(float* x, const float* __restrict__ g,
                                                     int C) {
  int t = blockIdx.x, tid = threadIdx.x;
  float* row = x + (long long)t * C;
  float ss = 0.f;
  for (int i = tid; i < C; i += 256) { float v = row[i]; ss += v * v; }
  __shared__ float red[4];
  ss = wave_sum64(ss);
  if ((tid & 63) == 0) red[tid >> 6] = ss;
  __syncthreads();
  float sc = rsqrtf((red[0] + red[1] + red[2] + red[3]) / (float)C + 1e-6f);
  for (int i = tid; i < C; i += 256) row[i] = row[i] * sc * g[i];
}

// ================= skv build -> bf16; row T_ = 0 =================
__global__ __launch_bounds__(256) void skv_build_k(const float* __restrict__ ckv,
                                                   const float* __restrict__ g,
                                                   const float* __restrict__ cosb,
                                                   const float* __restrict__ sinb,
                                                   __hip_bfloat16* __restrict__ skv) {
  int t = blockIdx.x, tid = threadIdx.x;
  __hip_bfloat16* out = skv + (long long)t * 576;
  if (t == T_) { for (int i = tid; i < 576; i += 256) out[i] = __float2bfloat16(0.f); return; }
  const float* row = ckv + (long long)t * 576;
  float ss = 0.f;
  for (int i = tid; i < 512; i += 256) { float v = row[i]; ss += v * v; }
  __shared__ float red[4];
  ss = wave_sum64(ss);
  if ((tid & 63) == 0) red[tid >> 6] = ss;
  __syncthreads();
  float sc = rsqrtf((red[0] + red[1] + red[2] + red[3]) / 512.f + 1e-6f);
  for (int i = tid; i < 512; i += 256) out[i] = __float2bfloat16(row[i] * sc * g[i]);
  if (tid < 64) {
    int j = tid, j2 = tid & 31;
    float c = cosb[t * 64 + j], s = sinb[t * 64 + j];
    float a = row[512 + 2 * j2], b = row[512 + 2 * j2 + 1];
    out[512 + j] = __float2bfloat16((j < 32) ? (a * c - b * s) : (a * s + b * c));
  }
}

// ================= rope in-place on qi heads (fp32) =================
__global__ __launch_bounds__(64) void rope_qi_k(float* qi, const float* __restrict__ cosb,
                                                const float* __restrict__ sinb) {
  int b = blockIdx.x, t = b >> 4, j = threadIdx.x, j2 = j & 31;
  float* x = qi + (long long)b * DI_;
  float c = cosb[t * 64 + j], s = sinb[t * 64 + j];
  float a = x[2 * j2], bb = x[2 * j2 + 1];
  float o = (j < 32) ? (a * c - bb * s) : (a * s + bb * c);
  x[j] = o;
}

// ================= ki: LayerNorm then rope, in-place (fp32) =================
__global__ __launch_bounds__(128) void ki_ln_rope_k(float* kbuf, const float* __restrict__ w,
                                                    const float* __restrict__ bia,
                                                    const float* __restrict__ cosb,
                                                    const float* __restrict__ sinb) {
  int t = blockIdx.x, i = threadIdx.x;
  float* row = kbuf + (long long)t * DI_;
  float x = row[i];
  __shared__ float red[2];
  float s1 = wave_sum64(x);
  if ((i & 63) == 0) red[i >> 6] = s1;
  __syncthreads();
  float mean = (red[0] + red[1]) / 128.f;
  float d = x - mean;
  __syncthreads();
  float s2 = wave_sum64(d * d);
  if ((i & 63) == 0) red[i >> 6] = s2;
  __syncthreads();
  float var = (red[0] + red[1]) / 128.f;
  float y = d * rsqrtf(var + 1e-6f) * w[i] + bia[i];
  __shared__ float rowl[128];
  rowl[i] = y;
  __syncthreads();
  float outv = y;
  if (i < 64) {
    int j2 = i & 31;
    float c = cosb[t * 64 + i], s = sinb[t * 64 + i];
    float a = rowl[2 * j2], b = rowl[2 * j2 + 1];
    outv = (i < 32) ? (a * c - b * s) : (a * s + b * c);
  }
  row[i] = outv;
}

// ================= rope q_full tail (bf16 in) -> sq_bf[...,512:576] =================
__global__ __launch_bounds__(64) void rope_q_sq_k(const __hip_bfloat16* __restrict__ qfull,
                                                  const float* __restrict__ cosb,
                                                  const float* __restrict__ sinb,
                                                  __hip_bfloat16* __restrict__ sq) {
  int b = blockIdx.x, t = b >> 4, h = b & 15, j = threadIdx.x, j2 = j & 31;
  const __hip_bfloat16* x = qfull + (long long)t * 3072 + h * 192 + 128;
  float c = cosb[t * 64 + j], s = sinb[t * 64 + j];
  float a = __bfloat162float(x[2 * j2]), bb = __bfloat162float(x[2 * j2 + 1]);
  float o = (j < 32) ? (a * c - bb * s) : (a * s + bb * c);
  sq[((long long)t * H_ + h) * 576 + 512 + j] = __float2bfloat16(o);
}

// ================= w = hidden @ i_wproj.T (fp32) =================
__global__ __launch_bounds__(256) void wproj_k(const float* __restrict__ hidden,
                                               const float* __restrict__ wp,
                                               float* __restrict__ out) {
  int wave = threadIdx.x >> 6, lane = threadIdx.x & 63;
  int t = blockIdx.x * 4 + wave;
  const float4* x4 = (const float4*)(hidden + (long long)t * 2048);
  float acc[16] = {};
  for (int c = lane; c < 512; c += 64) {
    float4 xv = x4[c];
#pragma unroll
    for (int h = 0; h < 16; ++h) {
      float4 wv = ((const float4*)(wp + h * 2048))[c];
      acc[h] += xv.x * wv.x + xv.y * wv.y + xv.z * wv.z + xv.w * wv.w;
    }
  }
#pragma unroll
  for (int h = 0; h < 16; ++h) {
    float s = wave_sum64(acc[h]);
    if (lane == 0) out[t * 16 + h] = s;
  }
}

// ========== exact radix-select top-256 — keys in registers, ballot-aggregated atomics ======
__global__ __launch_bounds__(256) void topk_k(const float* __restrict__ scores,
                                              int* __restrict__ indices)
{
  __shared__ unsigned s_hist[256];
  __shared__ unsigned s_wsum[4];
  __shared__ unsigned s_binsel[2];
  __shared__ unsigned s_cnt;
  const int t = blockIdx.x, tid = threadIdx.x;
  const int wave = tid >> 6, lane = tid & 63;
  const int i0 = tid * 4;
  if (tid == 0) s_cnt = 0;

  float4 sv = ((const float4*)(scores + t * T_))[tid];
  float f[4] = {sv.x, sv.y, sv.z, sv.w};
  unsigned key[4];
#pragma unroll
  for (int j = 0; j < 4; ++j) {
    unsigned u = __float_as_uint(f[j]);
    key[j] = (u & 0x80000000u) ? ~u : (u | 0x80000000u);
  }

  unsigned prefix = 0, Gprev = 0;
  for (int lvl = 0; lvl < 4; ++lvl) {
    const int shift = 24 - 8 * lvl;
    s_hist[tid] = 0;
    __syncthreads();
#pragma unroll
    for (int j = 0; j < 4; ++j) {
      unsigned k = key[j];
      bool part = (lvl == 0) || ((k >> (shift + 8)) == prefix);
      unsigned bin = (k >> shift) & 255u;
      unsigned long long mask = __ballot(part);
#pragma unroll
      for (int b = 0; b < 8; ++b) {
        unsigned long long bal = __ballot((bin >> b) & 1u);
        mask &= ((bin >> b) & 1u) ? bal : ~bal;
      }
      if (part && lane == (__ffsll((long long)mask) - 1))
        atomicAdd(&s_hist[bin], (unsigned)__popcll(mask));
    }
    __syncthreads();
    unsigned h = s_hist[255 - tid];
    unsigned sc_ = h;
    for (int off = 1; off < 64; off <<= 1) {
      unsigned v = __shfl_up(sc_, off);
      if (lane >= off) sc_ += v;
    }
    if (lane == 63) s_wsum[wave] = sc_;
    __syncthreads();
    unsigned wo = 0;
    for (int w = 0; w < wave; ++w) wo += s_wsum[w];
    unsigned incl = sc_ + wo, excl = incl - h;
    unsigned Rn = 256 - Gprev;
    if (excl < Rn && Rn <= incl) { s_binsel[0] = 255 - (unsigned)tid; s_binsel[1] = excl; }
    __syncthreads();
    prefix = (prefix << 8) | s_binsel[0];
    Gprev += s_binsel[1];
  }
  const unsigned thr = prefix;
  const unsigned Rq = 256 - Gprev;
  const unsigned negfkey = ~__float_as_uint(NEGF);

  unsigned eqc = 0;
#pragma unroll
  for (int j = 0; j < 4; ++j) eqc += (key[j] == thr) ? 1u : 0u;
  unsigned esc = eqc;
  for (int off = 1; off < 64; off <<= 1) {
    unsigned v = __shfl_up(esc, off);
    if (lane >= off) esc += v;
  }
  if (lane == 63) s_wsum[wave] = esc;
  __syncthreads();
  unsigned eo = 0;
  for (int w = 0; w < wave; ++w) eo += s_wsum[w];
  unsigned rank = esc + eo - eqc;

#pragma unroll
  for (int j = 0; j < 4; ++j) {
    unsigned k = key[j];
    int outv = (k == negfkey) ? T_ : (i0 + j);
    bool gt = (k > thr);
    unsigned long long bal = __ballot(gt);
    if (bal) {
      int leader = __ffsll((long long)bal) - 1;
      unsigned base = 0;
      if (lane == leader) base = atomicAdd(&s_cnt, (unsigned)__popcll(bal));
      base = (unsigned)__shfl((int)base, leader);
      if (gt) {
        unsigned pre = (unsigned)__popcll(bal & ((1ull << lane) - 1ull));
        indices[t * TOPK_ + base + pre] = outv;
      }
    }
    if (!gt && k == thr) {
      if (rank < Rq) indices[t * TOPK_ + Gprev + rank] = outv;
      rank++;
    }
  }
}

// ========= MFMA gathered attention — 512 thr; GLL-pipelined QK; XOR-swizzled PV ===========
// QK: Q staged once to LDS (18.4 KB); gathered K tile [256][32] double-buffered via
// global_load_lds (per-lane gathered SOURCE, linear DEST) with vmcnt(2) pipelining —
// removes the per-step exposed L2 latency (VGPR-prefetch fails: allocator pins ~52).
// LDS union: [s_q 18432 | s_k 32768 | s_p 16448] (QK) aliased by s_vt 67584 (PV); s_pb apart.
#define SP_LD 257
#define PB_LD 264
#define VT_LD 264
__global__ __launch_bounds__(512) void attn_k(
    const short* __restrict__ sq, const short* __restrict__ skv,
    const int* __restrict__ indices, __hip_bfloat16* __restrict__ attn_out)
{
  __shared__ int s_ind[TOPK_];
  __shared__ __align__(16) char s_un[76096];
  short* s_q  = (short*)s_un;                  // [18][16][32] = 18432 B (QK)
  short* s_k  = (short*)(s_un + 18432);        // [2][256][32] = 32768 B (QK)
  float* s_p  = (float*)(s_un + 51200);        // [16][SP_LD]  = 16448 B (QK out .. pack)
  short* s_vt = (short*)s_un;                  // [2][64][VT_LD] = 67584 B (PV)
  short* s_pb = (short*)(s_un + 67648);        // [16][PB_LD]  =  8448 B (disjoint)
  const int t = blockIdx.x, tid = threadIdx.x;
  const int wave = tid >> 6, lane = tid & 63;
  const int m0 = lane & 15, quad = lane >> 4;
  if (tid < TOPK_) s_ind[tid] = indices[t * TOPK_ + tid];
  __syncthreads();

  // ---- stage Q [18 ksteps][16 rows][32 shorts] : chunk c = n*512 + tid ----
  {
#pragma unroll
    for (int n = 0; n < 2; ++n) {
      const int c = n * 512 + tid;
      const int qks = c >> 6, qrow = (c >> 2) & 15, qch = c & 3;
      GLL(sq + ((long long)t * H_ + qrow) * 576 + qks * 32 + qch * 8, s_q + c * 8);
    }
    if (tid < 128) {
      const int c = 1024 + tid;
      const int qks = c >> 6, qrow = (c >> 2) & 15, qch = c & 3;
      GLL(sq + ((long long)t * H_ + qrow) * 576 + qks * 32 + qch * 8, s_q + c * 8);
    }
  }

  // ---- QK^T: gathered-K GLL double-buffer; each wave owns 32 KV rows ----
  {
    const int jb = wave * 32;
    // staging sources: instr A covers rows jb..jb+15 (4 lanes/row), B covers jb+16..jb+31
    const int rA = s_ind[jb + (lane >> 2)];
    const int rB = s_ind[jb + 16 + (lane >> 2)];
    const short* pA = skv + (long long)rA * 576 + (lane & 3) * 8;
    const short* pB = skv + (long long)rB * 576 + (lane & 3) * 8;
    short* ldsA = s_k + wave * 1024 + lane * 8;          // wave-linear dest (base+lane*16B)
#define STAGE_K(buf, kstep) \
    GLL(pA + (kstep) * 32, ldsA + (buf) * 8192); \
    GLL(pB + (kstep) * 32, ldsA + (buf) * 8192 + 512);
    f32x4 qacc[2] = {};
    STAGE_K(0, 0);
    for (int ks = 0; ks < 18; ++ks) {
      const int cur = ks & 1;
      if (ks + 1 < 18) {
        STAGE_K(cur ^ 1, ks + 1);
        asm volatile("s_waitcnt vmcnt(2)\ns_barrier" ::: "memory");
      } else {
        asm volatile("s_waitcnt vmcnt(0)\ns_barrier" ::: "memory");
      }
      bfrag_t aq = *(const bfrag_t*)(s_q + ks * 512 + m0 * 32 + quad * 8);
#pragma unroll
      for (int j = 0; j < 2; ++j) {
        bfrag_t bq = *(const bfrag_t*)(s_k + cur * 8192 + (jb + j * 16 + m0) * 32 + quad * 8);
        qacc[j] = __builtin_amdgcn_mfma_f32_16x16x32_bf16(aq, bq, qacc[j], 0, 0, 0);
      }
      asm volatile("s_barrier" ::: "memory");
    }
#undef STAGE_K
    const float scale = 0.07216878364870322f;
#pragma unroll
    for (int j = 0; j < 2; ++j) {
      int key = jb + j * 16 + m0;
      bool msk = (s_ind[key] == T_);
#pragma unroll
      for (int r = 0; r < 4; ++r)
        s_p[(quad * 4 + r) * SP_LD + key] = msk ? NEGF : qacc[j][r] * scale;
    }
  }
  __syncthreads();

  // ---- softmax (2 heads per wave) ----
  for (int h = wave * 2; h < wave * 2 + 2; ++h) {
    float* ph = s_p + h * SP_LD;
    float m = -3.4e38f;
    for (int j = lane; j < TOPK_; j += 64) m = fmaxf(m, ph[j]);
#pragma unroll
    for (int off = 32; off; off >>= 1) m = fmaxf(m, __shfl_xor(m, off));
    float sum = 0.f;
    for (int j = lane; j < TOPK_; j += 64) {
      float e = __expf(ph[j] - m);
      ph[j] = e; sum += e;
    }
    sum = wave_sum64(sum);
    float inv = 1.f / sum;
    for (int j = lane; j < TOPK_; j += 64) ph[j] *= inv;
  }
  __syncthreads();

  // ---- pack P -> bf16 (s_pb fully disjoint) ----
  {
    const int col = tid & 255, h0 = tid >> 8;
#pragma unroll
    for (int h = 0; h < 8; ++h) {
      const int hh = h0 + h * 2;
      s_pb[hh * PB_LD + col] =
          (short)__bfloat16_as_ushort(__float2bfloat16(s_p[hh * SP_LD + col]));
    }
  }
  __syncthreads();

  bfrag_t apf[8];
#pragma unroll
  for (int kk = 0; kk < 8; ++kk)
    apf[kk] = *(const bfrag_t*)(s_pb + m0 * PB_LD + kk * 32 + quad * 8);

  // ---- PV: group = wave>>2 handles c in [grp*4, grp*4+4) with its own s_vt ----
  const int grp = wave >> 2, gw = wave & 3;
  short* svt = s_vt + grp * (64 * VT_LD);
  const int r8 = (tid >> 3) & 31;   // row slot within 256-thread group
  const int bb = tid & 7;           // 16B chunk within the 128B slab

  for (int cc = 0; cc < 4; ++cc) {
    const int c = grp * 4 + cc;
    __syncthreads();   // apf reads (first iter) / prev MFMA reads done; safe to overwrite svt
#pragma unroll
    for (int rep = 0; rep < 8; ++rep) {
      const int kv = r8 + 32 * rep;
      const int row = s_ind[kv];
      bfrag_t v = *(const bfrag_t*)(skv + (long long)row * 576 + c * 64 + bb * 8);
      const int colx = kv ^ (bb << 3);
#pragma unroll
      for (int j = 0; j < 8; ++j)
        svt[(bb * 8 + j) * VT_LD + colx] = v[j];
    }
    __syncthreads();
    const int d = gw * 16 + m0;
    const short* vrow = svt + d * VT_LD;
    const int sx = (d >> 3) << 3;
    f32x4 oacc = {0.f, 0.f, 0.f, 0.f};
#pragma unroll
    for (int kk = 0; kk < 8; ++kk) {
      bfrag_t bv = *(const bfrag_t*)(vrow + ((kk * 32 + quad * 8) ^ sx));
      oacc = __builtin_amdgcn_mfma_f32_16x16x32_bf16(apf[kk], bv, oacc, 0, 0, 0);
    }
    const int col = c * 64 + d;
#pragma unroll
    for (int r = 0; r < 4; ++r)
      attn_out[((long long)t * H_ + quad * 4 + r) * 512 + col] = __float2bfloat16(oacc[r]);
  }
}

extern "C" void kernel_launch(void* const* d_in, const int* in_sizes, int n_in,
                              void* d_out, int out_size, void* d_ws, size_t ws_size,
                              hipStream_t stream) {
  const float* hidden  = (const float*)d_in[0];
  const float* cosb    = (const float*)d_in[1];
  const float* sinb    = (const float*)d_in[2];
  const int*   ks      = (const int*)d_in[3];
  const int*   ke      = (const int*)d_in[4];
  const float* w_qa    = (const float*)d_in[5];
  const float* g_qa    = (const float*)d_in[6];
  const float* w_qb    = (const float*)d_in[7];
  const float* w_kva   = (const float*)d_in[8];
  const float* g_kva   = (const float*)d_in[9];
  const float* w_kvb   = (const float*)d_in[10];
  const float* w_o     = (const float*)d_in[11];
  const float* i_wqb   = (const float*)d_in[12];
  const float* i_wk    = (const float*)d_in[13];
  const float* i_ln_w  = (const float*)d_in[14];
  const float* i_ln_b  = (const float*)d_in[15];
  const float* i_wproj = (const float*)d_in[16];
  float* out = (float*)d_out;
  (void)in_sizes; (void)n_in; (void)out_size; (void)ws_size;

  // ---- workspace (bytes), lifetime-overlapped (layout verified R6) ----
  char* ws = (char*)d_ws;
  __hip_bfloat16* hid_hi  = (__hip_bfloat16*)(ws + 0);
  __hip_bfloat16* hid_lo  = (__hip_bfloat16*)(ws + 4194304);
  float*          q_lat   = (float*)(ws + 8388608);
  __hip_bfloat16* qi_hi   = (__hip_bfloat16*)(ws + 8388608);    // over dead q_lat
  __hip_bfloat16* qlat_hi = (__hip_bfloat16*)(ws + 14680064);
  __hip_bfloat16* qlat_lo = (__hip_bfloat16*)(ws + 17825792);
  float*          qi      = (float*)(ws + 20971520);
  float*          scoresb = (float*)(ws + 20971520);            // over dead qi (post-decomp)
  float*          kib     = (float*)(ws + 29360128);
  float*          wbuf    = (float*)(ws + 29884416);
  float*          ckv     = (float*)(ws + 29949952);
  __hip_bfloat16* qi_lo   = (__hip_bfloat16*)(ws + 29949952);   // over dead ckv
  __hip_bfloat16* ki_hi   = (__hip_bfloat16*)(ws + 34144256);
  __hip_bfloat16* ki_lo   = (__hip_bfloat16*)(ws + 34406400);
  __hip_bfloat16* sq_bf   = (__hip_bfloat16*)(ws + 0);
  __hip_bfloat16* o_bf    = (__hip_bfloat16*)(ws + 0);
  __hip_bfloat16* W       = (__hip_bfloat16*)(ws + 37748736);
  __hip_bfloat16* skv_bf  = (__hip_bfloat16*)(ws + 47185920);
  int*            idxb    = (int*)(ws + 48366720);
  __hip_bfloat16* E       = (__hip_bfloat16*)(ws + 49415296);

  dim3 blk(256);
  const short* Ws = (const short*)W;
  const short* Es = (const short*)E;

  decomp_k<<<2048, blk, 0, stream>>>(hidden, hid_hi, hid_lo, 524288);

  // ---- q_lat = hidden @ w_qa^T (split-K=4: 384 blocks) ----
  decomp_k<<<3072, blk, 0, stream>>>(w_qa, W, E, 786432);
  zero_k<<<1536, blk, 0, stream>>>((float4*)q_lat, 393216);
  gemm3_k<<<dim3(12, 8, 4), blk, 0, stream>>>(
      (const short*)hid_hi, (const short*)hid_lo, HID_, Ws, Es, HID_, q_lat, LQ_, LQ_, 512);
  rms_inplace_k<<<T_, blk, 0, stream>>>(q_lat, g_qa, LQ_);

  // ---- ckv = hidden @ w_kva^T (split-K=4: 160 blocks) ----
  cast_pad_k<<<1280, blk, 0, stream>>>(w_kva, W, 576, 512, 640);
  zero_k<<<576, blk, 0, stream>>>((float4*)ckv, 147456);
  gemm_bfs_k<<<dim3(5, 8, 4), blk, 0, stream>>>(
      (const short*)hid_hi, HID_, Ws, HID_, ckv, 576, 576, 512);
  skv_build_k<<<T_ + 1, blk, 0, stream>>>(ckv, g_kva, cosb, sinb, skv_bf);

  decomp_k<<<1536, blk, 0, stream>>>(q_lat, qlat_hi, qlat_lo, 393216);

  // ---- qi = q_lat @ i_wqb^T (split-K=4: 512 blocks) ----
  decomp_k<<<3072, blk, 0, stream>>>(i_wqb, W, E, 786432);
  zero_k<<<2048, blk, 0, stream>>>((float4*)qi, 524288);
  gemm3_k<<<dim3(16, 8, 4), blk, 0, stream>>>(
      (const short*)qlat_hi, (const short*)qlat_lo, LQ_, Ws, Es, LQ_, qi, HI_ * DI_, HI_ * DI_, 384);
  rope_qi_k<<<T_ * HI_, dim3(64), 0, stream>>>(qi, cosb, sinb);
  decomp_k<<<2048, blk, 0, stream>>>(qi, qi_hi, qi_lo, 524288);

  // ---- kib = hidden @ i_wk^T (split-K=16: 128 blocks) ----
  decomp_k<<<256, blk, 0, stream>>>(i_wk, W, E, 65536);
  zero_k<<<128, blk, 0, stream>>>((float4*)kib, 32768);
  gemm3_k<<<dim3(1, 8, 16), blk, 0, stream>>>(
      (const short*)hid_hi, (const short*)hid_lo, HID_, Ws, Es, HID_, kib, DI_, DI_, 128);
  ki_ln_rope_k<<<T_, dim3(128), 0, stream>>>(kib, i_ln_w, i_ln_b, cosb, sinb);
  decomp_k<<<128, blk, 0, stream>>>(kib, ki_hi, ki_lo, 32768);

  wproj_k<<<256, blk, 0, stream>>>(hidden, i_wproj, wbuf);

  // ---- indexer: GEMM-shaped scores (GLL pipeline) then register-key radix select ----
  score_gemm_k<<<dim3(8, 128), blk, 0, stream>>>(
      (const short*)qi_hi, (const short*)qi_lo, (const short*)ki_hi, (const short*)ki_lo,
      wbuf, ks, ke, scoresb);
  topk_k<<<T_, blk, 0, stream>>>(scoresb, idxb);

  cast_bf16_k<<<4608, blk, 0, stream>>>(w_qb, W, 1179648);
  gemm_bf_k<__hip_bfloat16><<<dim3(24, 8, 1), blk, 0, stream>>>(
      (const short*)qlat_hi, LQ_, 0, Ws, LQ_, 0, (__hip_bfloat16*)E, H_ * DQ_, 0, H_ * DQ_, LQ_);
  rope_q_sq_k<<<T_ * H_, dim3(64), 0, stream>>>(E, cosb, sinb, sq_bf);

  wkn_t_k<<<dim3(2, 8, 16), blk, 0, stream>>>(w_kvb, W);
  gemm_bf_k<__hip_bfloat16><<<dim3(4, 8, 16), blk, 0, stream>>>(
      Es, H_ * DQ_, 192, Ws, DI_, 65536, sq_bf, H_ * 576, 576, LKV_, DN_);

  attn_k<<<T_, dim3(512), 0, stream>>>((const short*)sq_bf, (const short*)skv_bf, idxb, E);

  wv_cast_k<<<4096, blk, 0, stream>>>(w_kvb, W);
  gemm_bf_k<__hip_bfloat16><<<dim3(1, 8, 16), blk, 0, stream>>>(
      Es, H_ * LKV_, 512, Ws, LKV_, 65536, o_bf, H_ * DV_, 128, DV_, LKV_);

  // ---- out = o_bf @ w_o^T (split-K=4: 512 blocks) ----
  cast_bf16_k<<<4096, blk, 0, stream>>>(w_o, W, 1048576);
  zero_k<<<2048, blk, 0, stream>>>((float4*)out, 524288);
  gemm_bfs_k<<<dim3(16, 8, 4), blk, 0, stream>>>(
      (const short*)o_bf, H_ * DV_, Ws, H_ * DV_, out, HID_, HID_, 512);
}

// Round 10
// 527.522 us; speedup vs baseline: 1.1332x; 1.0071x over previous
//
#include <hip/hip_runtime.h>
#include <hip/hip_bf16.h>
#include <cmath>

#define T_ 1024
#define HID_ 2048
#define H_ 16
#define LQ_ 1536
#define LKV_ 512
#define DR_ 64
#define DN_ 128
#define DQ_ 192
#define DV_ 128
#define HI_ 16
#define DI_ 128
#define TOPK_ 256
#define NEGF (-1e30f)

typedef short bfrag_t __attribute__((ext_vector_type(8)));   // 8 bf16 = 4 VGPRs
typedef float f32x4 __attribute__((ext_vector_type(4)));

__device__ __forceinline__ float wave_sum64(float v) {
#pragma unroll
  for (int off = 32; off; off >>= 1) v += __shfl_xor(v, off);
  return v;
}

#define GLL(g, l) __builtin_amdgcn_global_load_lds((const __attribute__((address_space(1))) void*)(g), \
                                     (__attribute__((address_space(3))) void*)(l), 16, 0, 0)

// ================= zero fill (for split-K atomic accumulation) =================
__global__ __launch_bounds__(256) void zero_k(float4* __restrict__ p, int n4) {
  int i = blockIdx.x * 256 + threadIdx.x;
  if (i < n4) p[i] = make_float4(0.f, 0.f, 0.f, 0.f);
}

// ================= bf16 MFMA GEMM: C = A @ B^T — double-buffered, raw-barrier pipeline ====
template<typename CT>
__global__ __launch_bounds__(256) void gemm_bf_k(
    const short* __restrict__ A, int lda, long long sA,
    const short* __restrict__ B, int ldb, long long sB,
    CT* __restrict__ C, int ldc, long long sC,
    int Nout, int K)
{
  __shared__ short As[2][128 * 32];
  __shared__ short Bs[2][128 * 32];
  A += (long long)blockIdx.z * sA;
  B += (long long)blockIdx.z * sB;
  C += (long long)blockIdx.z * sC;
  const int tid = threadIdx.x;
  const int bm = blockIdx.y * 128, bn = blockIdx.x * 128;
  const int wave = tid >> 6, lane = tid & 63;
  const int wm = (wave >> 1) * 64, wn = (wave & 1) * 64;
  const int sr = tid >> 2;
  const int scol = (tid & 3) * 8;
  const int m0 = lane & 15, koff = (lane >> 4) * 8;
  f32x4 acc[4][4] = {};
  const short* ga = A + (long long)(bm + sr) * lda + scol;
  const short* gb = B + (long long)(bn + sr) * ldb + scol;
#define STAGE_BF(buf, off) \
    GLL(ga + (off), As[buf] + tid * 8); GLL(ga + (off) + 64 * lda, As[buf] + tid * 8 + 2048); \
    GLL(gb + (off), Bs[buf] + tid * 8); GLL(gb + (off) + 64 * ldb, Bs[buf] + tid * 8 + 2048);
  const int niter = K >> 5;
  STAGE_BF(0, 0);
  for (int it = 0; it < niter; ++it) {
    const int cur = it & 1;
    if (it + 1 < niter) {
      STAGE_BF(cur ^ 1, (it + 1) * 32);
      asm volatile("s_waitcnt vmcnt(4)\ns_barrier" ::: "memory");
    } else {
      asm volatile("s_waitcnt vmcnt(0)\ns_barrier" ::: "memory");
    }
    bfrag_t af[4], bfv[4];
#pragma unroll
    for (int i = 0; i < 4; ++i)
      af[i] = *(const bfrag_t*)(As[cur] + (wm + i * 16 + m0) * 32 + koff);
#pragma unroll
    for (int j = 0; j < 4; ++j)
      bfv[j] = *(const bfrag_t*)(Bs[cur] + (wn + j * 16 + m0) * 32 + koff);
#pragma unroll
    for (int i = 0; i < 4; ++i)
#pragma unroll
      for (int j = 0; j < 4; ++j)
        acc[i][j] = __builtin_amdgcn_mfma_f32_16x16x32_bf16(af[i], bfv[j], acc[i][j], 0, 0, 0);
    asm volatile("s_barrier" ::: "memory");
  }
#undef STAGE_BF
  const int cr = (lane >> 4) * 4, cc = lane & 15;
#pragma unroll
  for (int i = 0; i < 4; ++i) {
    int row = bm + wm + i * 16 + cr;
#pragma unroll
    for (int j = 0; j < 4; ++j) {
      int col = bn + wn + j * 16 + cc;
      if (col < Nout) {
#pragma unroll
        for (int r = 0; r < 4; ++r)
          C[(long long)(row + r) * ldc + col] = (CT)(acc[i][j][r]);
      }
    }
  }
}

// ====== bf16 GEMM, fp32 out, split-K over blockIdx.z with atomic accumulate ======
__global__ __launch_bounds__(256) void gemm_bfs_k(
    const short* __restrict__ A, int lda,
    const short* __restrict__ B, int ldb,
    float* __restrict__ C, int ldc, int Nout, int K)
{
  __shared__ short As[2][128 * 32];
  __shared__ short Bs[2][128 * 32];
  const long long kbase = (long long)blockIdx.z * K;
  const int tid = threadIdx.x;
  const int bm = blockIdx.y * 128, bn = blockIdx.x * 128;
  const int wave = tid >> 6, lane = tid & 63;
  const int wm = (wave >> 1) * 64, wn = (wave & 1) * 64;
  const int sr = tid >> 2;
  const int scol = (tid & 3) * 8;
  const int m0 = lane & 15, koff = (lane >> 4) * 8;
  f32x4 acc[4][4] = {};
  const short* ga = A + (long long)(bm + sr) * lda + kbase + scol;
  const short* gb = B + (long long)(bn + sr) * ldb + kbase + scol;
#define STAGE_BS(buf, off) \
    GLL(ga + (off), As[buf] + tid * 8); GLL(ga + (off) + 64 * lda, As[buf] + tid * 8 + 2048); \
    GLL(gb + (off), Bs[buf] + tid * 8); GLL(gb + (off) + 64 * ldb, Bs[buf] + tid * 8 + 2048);
  const int niter = K >> 5;
  STAGE_BS(0, 0);
  for (int it = 0; it < niter; ++it) {
    const int cur = it & 1;
    if (it + 1 < niter) {
      STAGE_BS(cur ^ 1, (it + 1) * 32);
      asm volatile("s_waitcnt vmcnt(4)\ns_barrier" ::: "memory");
    } else {
      asm volatile("s_waitcnt vmcnt(0)\ns_barrier" ::: "memory");
    }
    bfrag_t af[4], bfv[4];
#pragma unroll
    for (int i = 0; i < 4; ++i)
      af[i] = *(const bfrag_t*)(As[cur] + (wm + i * 16 + m0) * 32 + koff);
#pragma unroll
    for (int j = 0; j < 4; ++j)
      bfv[j] = *(const bfrag_t*)(Bs[cur] + (wn + j * 16 + m0) * 32 + koff);
#pragma unroll
    for (int i = 0; i < 4; ++i)
#pragma unroll
      for (int j = 0; j < 4; ++j)
        acc[i][j] = __builtin_amdgcn_mfma_f32_16x16x32_bf16(af[i], bfv[j], acc[i][j], 0, 0, 0);
    asm volatile("s_barrier" ::: "memory");
  }
#undef STAGE_BS
  const int cr = (lane >> 4) * 4, cc = lane & 15;
#pragma unroll
  for (int i = 0; i < 4; ++i) {
    int row = bm + wm + i * 16 + cr;
#pragma unroll
    for (int j = 0; j < 4; ++j) {
      int col = bn + wn + j * 16 + cc;
      if (col < Nout) {
#pragma unroll
        for (int r = 0; r < 4; ++r)
          atomicAdd(&C[(long long)(row + r) * ldc + col], acc[i][j][r]);
      }
    }
  }
}

// ====== bf16x3 split GEMM (fp32-accurate) — double-buffered, split-K capable ======
__global__ __launch_bounds__(256) void gemm3_k(
    const short* __restrict__ Ah, const short* __restrict__ Al, int lda,
    const short* __restrict__ Bh, const short* __restrict__ Bl, int ldb,
    float* __restrict__ C, int ldc, int Nout, int K)
{
  __shared__ short Ahs[2][128 * 32];
  __shared__ short Als[2][128 * 32];
  __shared__ short Bhs[2][128 * 32];
  __shared__ short Bls[2][128 * 32];
  const long long kbase = (long long)blockIdx.z * K;
  const int tid = threadIdx.x;
  const int bm = blockIdx.y * 128, bn = blockIdx.x * 128;
  const int wave = tid >> 6, lane = tid & 63;
  const int wm = (wave >> 1) * 64, wn = (wave & 1) * 64;
  const int sr = tid >> 2;
  const int scol = (tid & 3) * 8;
  const int m0 = lane & 15, koff = (lane >> 4) * 8;
  f32x4 acc[4][4] = {};
  const short* gah = Ah + (long long)(bm + sr) * lda + kbase + scol;
  const short* gal = Al + (long long)(bm + sr) * lda + kbase + scol;
  const short* gbh = Bh + (long long)(bn + sr) * ldb + kbase + scol;
  const short* gbl = Bl + (long long)(bn + sr) * ldb + kbase + scol;
#define STAGE_3(buf, off) \
    GLL(gah + (off), Ahs[buf] + tid * 8); GLL(gah + (off) + 64 * lda, Ahs[buf] + tid * 8 + 2048); \
    GLL(gal + (off), Als[buf] + tid * 8); GLL(gal + (off) + 64 * lda, Als[buf] + tid * 8 + 2048); \
    GLL(gbh + (off), Bhs[buf] + tid * 8); GLL(gbh + (off) + 64 * ldb, Bhs[buf] + tid * 8 + 2048); \
    GLL(gbl + (off), Bls[buf] + tid * 8); GLL(gbl + (off) + 64 * ldb, Bls[buf] + tid * 8 + 2048);
  const int niter = K >> 5;
  STAGE_3(0, 0);
  for (int it = 0; it < niter; ++it) {
    const int cur = it & 1;
    if (it + 1 < niter) {
      STAGE_3(cur ^ 1, (it + 1) * 32);
      asm volatile("s_waitcnt vmcnt(8)\ns_barrier" ::: "memory");
    } else {
      asm volatile("s_waitcnt vmcnt(0)\ns_barrier" ::: "memory");
    }
    bfrag_t afh[4], afl[4], bfh[4], bfl[4];
#pragma unroll
    for (int i = 0; i < 4; ++i) {
      afh[i] = *(const bfrag_t*)(Ahs[cur] + (wm + i * 16 + m0) * 32 + koff);
      afl[i] = *(const bfrag_t*)(Als[cur] + (wm + i * 16 + m0) * 32 + koff);
    }
#pragma unroll
    for (int j = 0; j < 4; ++j) {
      bfh[j] = *(const bfrag_t*)(Bhs[cur] + (wn + j * 16 + m0) * 32 + koff);
      bfl[j] = *(const bfrag_t*)(Bls[cur] + (wn + j * 16 + m0) * 32 + koff);
    }
    // term-grouped: no back-to-back MFMAs on the same accumulator (per-acc fp32
    // add order unchanged: hh, hl, lh within each K-iter -> bit-identical)
#pragma unroll
    for (int i = 0; i < 4; ++i)
#pragma unroll
      for (int j = 0; j < 4; ++j)
        acc[i][j] = __builtin_amdgcn_mfma_f32_16x16x32_bf16(afh[i], bfh[j], acc[i][j], 0, 0, 0);
#pragma unroll
    for (int i = 0; i < 4; ++i)
#pragma unroll
      for (int j = 0; j < 4; ++j)
        acc[i][j] = __builtin_amdgcn_mfma_f32_16x16x32_bf16(afh[i], bfl[j], acc[i][j], 0, 0, 0);
#pragma unroll
    for (int i = 0; i < 4; ++i)
#pragma unroll
      for (int j = 0; j < 4; ++j)
        acc[i][j] = __builtin_amdgcn_mfma_f32_16x16x32_bf16(afl[i], bfh[j], acc[i][j], 0, 0, 0);
    asm volatile("s_barrier" ::: "memory");
  }
#undef STAGE_3
  const int cr = (lane >> 4) * 4, cc = lane & 15;
  const bool spl = (gridDim.z > 1);
#pragma unroll
  for (int i = 0; i < 4; ++i) {
    int row = bm + wm + i * 16 + cr;
#pragma unroll
    for (int j = 0; j < 4; ++j) {
      int col = bn + wn + j * 16 + cc;
      if (col < Nout) {
#pragma unroll
        for (int r = 0; r < 4; ++r) {
          if (spl) atomicAdd(&C[(long long)(row + r) * ldc + col], acc[i][j][r]);
          else     C[(long long)(row + r) * ldc + col] = acc[i][j][r];
        }
      }
    }
  }
}

// ====== indexer scores as a GEMM: logits = qi @ ki^T (bf16x3, M=16384 N=1024 K=128) ======
__global__ __launch_bounds__(256) void score_gemm_k(
    const short* __restrict__ Ah, const short* __restrict__ Al,   // qi_hi/lo [16384][128]
    const short* __restrict__ Bh, const short* __restrict__ Bl,   // ki_hi/lo [1024][128]
    const float* __restrict__ wproj, const int* __restrict__ ks,
    const int* __restrict__ ke, float* __restrict__ scores)
{
  __shared__ short Ahs[2][128 * 32];
  __shared__ short Als[2][128 * 32];
  __shared__ short Bhs[2][128 * 32];
  __shared__ short Bls[2][128 * 32];
  __shared__ float s_w[8][16];
  __shared__ int s_ks[8], s_ke[8];
  const int tid = threadIdx.x;
  const int bm = blockIdx.y * 128, bn = blockIdx.x * 128;
  const int wave = tid >> 6, lane = tid & 63;
  const int wm = (wave >> 1) * 64, wn = (wave & 1) * 64;
  const int sr = tid >> 2;
  const int scol = (tid & 3) * 8;
  const int m0 = lane & 15, koff = (lane >> 4) * 8;
  const int t0 = bm >> 4;   // first of this tile's 8 tokens
  if (tid < 128) s_w[tid >> 4][tid & 15] =
      wproj[(t0 + (tid >> 4)) * HI_ + (tid & 15)] * 0.022097086912079608f;
  if (tid < 8) { s_ks[tid] = ks[t0 + tid]; s_ke[tid] = ke[t0 + tid]; }
  f32x4 acc[4][4] = {};
  const short* gah = Ah + (long long)(bm + sr) * DI_ + scol;
  const short* gal = Al + (long long)(bm + sr) * DI_ + scol;
  const short* gbh = Bh + (long long)(bn + sr) * DI_ + scol;
  const short* gbl = Bl + (long long)(bn + sr) * DI_ + scol;
#define STAGE_S(buf, off) \
    GLL(gah + (off), Ahs[buf] + tid * 8); GLL(gah + (off) + 64 * DI_, Ahs[buf] + tid * 8 + 2048); \
    GLL(gal + (off), Als[buf] + tid * 8); GLL(gal + (off) + 64 * DI_, Als[buf] + tid * 8 + 2048); \
    GLL(gbh + (off), Bhs[buf] + tid * 8); GLL(gbh + (off) + 64 * DI_, Bhs[buf] + tid * 8 + 2048); \
    GLL(gbl + (off), Bls[buf] + tid * 8); GLL(gbl + (off) + 64 * DI_, Bls[buf] + tid * 8 + 2048);
  const int niter = DI_ >> 5;   // 4
  STAGE_S(0, 0);
  for (int it = 0; it < niter; ++it) {
    const int cur = it & 1;
    if (it + 1 < niter) {
      STAGE_S(cur ^ 1, (it + 1) * 32);
      asm volatile("s_waitcnt vmcnt(8)\ns_barrier" ::: "memory");
    } else {
      asm volatile("s_waitcnt vmcnt(0)\ns_barrier" ::: "memory");
    }
    bfrag_t afh[4], afl[4], bfh[4], bfl[4];
#pragma unroll
    for (int i = 0; i < 4; ++i) {
      afh[i] = *(const bfrag_t*)(Ahs[cur] + (wm + i * 16 + m0) * 32 + koff);
      afl[i] = *(const bfrag_t*)(Als[cur] + (wm + i * 16 + m0) * 32 + koff);
    }
#pragma unroll
    for (int j = 0; j < 4; ++j) {
      bfh[j] = *(const bfrag_t*)(Bhs[cur] + (wn + j * 16 + m0) * 32 + koff);
      bfl[j] = *(const bfrag_t*)(Bls[cur] + (wn + j * 16 + m0) * 32 + koff);
    }
#pragma unroll
    for (int i = 0; i < 4; ++i)
#pragma unroll
      for (int j = 0; j < 4; ++j)
        acc[i][j] = __builtin_amdgcn_mfma_f32_16x16x32_bf16(afh[i], bfh[j], acc[i][j], 0, 0, 0);
#pragma unroll
    for (int i = 0; i < 4; ++i)
#pragma unroll
      for (int j = 0; j < 4; ++j)
        acc[i][j] = __builtin_amdgcn_mfma_f32_16x16x32_bf16(afh[i], bfl[j], acc[i][j], 0, 0, 0);
#pragma unroll
    for (int i = 0; i < 4; ++i)
#pragma unroll
      for (int j = 0; j < 4; ++j)
        acc[i][j] = __builtin_amdgcn_mfma_f32_16x16x32_bf16(afl[i], bfh[j], acc[i][j], 0, 0, 0);
    asm volatile("s_barrier" ::: "memory");
  }
#undef STAGE_S
  const int cc = lane & 15, quad = lane >> 4;
#pragma unroll
  for (int i = 0; i < 4; ++i) {
    const int g = (wm >> 4) + i;          // token slot 0..7 within the tile
    const int tok = t0 + g;
    const int lo = s_ks[g], hi = s_ke[g];
#pragma unroll
    for (int j = 0; j < 4; ++j) {
      float sc = 0.f;
#pragma unroll
      for (int r = 0; r < 4; ++r)
        sc += fmaxf(acc[i][j][r], 0.f) * s_w[g][quad * 4 + r];
      sc += __shfl_xor(sc, 16);
      sc += __shfl_xor(sc, 32);
      if (quad == 0) {
        const int s = bn + wn + j * 16 + cc;
        scores[tok * T_ + s] = (s >= lo && s <= hi) ? sc : NEGF;
      }
    }
  }
}

// ================= casts / decompose =================
__global__ __launch_bounds__(256) void cast_bf16_k(const float* __restrict__ src,
                                                   __hip_bfloat16* __restrict__ dst, int n4) {
  int i = blockIdx.x * 256 + threadIdx.x;
  if (i >= n4) return;
  float4 v = ((const float4*)src)[i];
  union { ushort4 u; __hip_bfloat16 h[4]; } o;
  o.h[0] = __float2bfloat16(v.x); o.h[1] = __float2bfloat16(v.y);
  o.h[2] = __float2bfloat16(v.z); o.h[3] = __float2bfloat16(v.w);
  ((ushort4*)dst)[i] = o.u;
}

__global__ __launch_bounds__(256) void decomp_k(const float* __restrict__ src,
                                                __hip_bfloat16* __restrict__ hi,
                                                __hip_bfloat16* __restrict__ lo, int n4) {
  int i = blockIdx.x * 256 + threadIdx.x;
  if (i >= n4) return;
  float4 v = ((const float4*)src)[i];
  float f[4] = {v.x, v.y, v.z, v.w};
  union { ushort4 u; __hip_bfloat16 h[4]; } oh, ol;
#pragma unroll
  for (int j = 0; j < 4; ++j) {
    __hip_bfloat16 h = __float2bfloat16(f[j]);
    oh.h[j] = h;
    ol.h[j] = __float2bfloat16(f[j] - __bfloat162float(h));
  }
  ((ushort4*)hi)[i] = oh.u;
  ((ushort4*)lo)[i] = ol.u;
}

__global__ __launch_bounds__(256) void cast_pad_k(const float* __restrict__ src,
                                                  __hip_bfloat16* __restrict__ dst,
                                                  int N, int K4, int Npad) {
  int i = blockIdx.x * 256 + threadIdx.x;
  if (i >= Npad * K4) return;
  int r = i / K4;
  float4 v = make_float4(0.f, 0.f, 0.f, 0.f);
  if (r < N) v = ((const float4*)src)[i];
  union { ushort4 u; __hip_bfloat16 h[4]; } o;
  o.h[0] = __float2bfloat16(v.x); o.h[1] = __float2bfloat16(v.y);
  o.h[2] = __float2bfloat16(v.z); o.h[3] = __float2bfloat16(v.w);
  ((ushort4*)dst)[i] = o.u;
}

// w_kn transposed-cast via LDS 64x64 tile: dst[h][k][d] = w_kvb[(h*256+d)*512+k]
__global__ __launch_bounds__(256) void wkn_t_k(const float* __restrict__ wkvb,
                                               __hip_bfloat16* __restrict__ dst) {
  __shared__ float tile[64][65];
  const int h = blockIdx.z, k0 = blockIdx.y * 64, d0 = blockIdx.x * 64;
  const int c = threadIdx.x & 63, r0 = threadIdx.x >> 6;
#pragma unroll
  for (int rr = 0; rr < 16; ++rr) {
    int r = r0 + rr * 4;
    tile[r][c] = wkvb[((h * 256 + d0 + r) << 9) + k0 + c];  // coalesced (k fast)
  }
  __syncthreads();
#pragma unroll
  for (int rr = 0; rr < 16; ++rr) {
    int r = r0 + rr * 4;   // k-local
    dst[((h * 512 + k0 + r) << 7) + d0 + c] = __float2bfloat16(tile[c][r]); // coalesced (d fast)
  }
}

__global__ __launch_bounds__(256) void wv_cast_k(const float* __restrict__ wkvb,
                                                 __hip_bfloat16* __restrict__ dst) {
  int i = blockIdx.x * 256 + threadIdx.x;
  int k = i & 511, dv = (i >> 9) & 127, h = i >> 16;
  dst[i] = __float2bfloat16(wkvb[((h * 256 + 128 + dv) << 9) + k]);
}

// ================= RMSNorm in-place (fp32) =================
__global__ __launch_bounds__(256) void rms_inplace_k(float* x, const float* __restrict__ g,
                                                     int C) {
  int t = blockIdx.x, tid = threadIdx.x;
  float* row = x + (long long)t * C;
  float ss = 0.f;
  for (int i = tid; i < C; i += 256) { float v = row[i]; ss += v * v; }
  __shared__ float red[4];
  ss = wave_sum64(ss);
  if ((tid & 63) == 0) red[tid >> 6] = ss;
  __syncthreads();
  float sc = rsqrtf((red[0] + red[1] + red[2] + red[3]) / (float)C + 1e-6f);
  for (int i = tid; i < C; i += 256) row[i] = row[i] * sc * g[i];
}

// ================= skv build -> bf16; row T_ = 0 =================
__global__ __launch_bounds__(256) void skv_build_k(const float* __restrict__ ckv,
                                                   const float* __restrict__ g,
                                                   const float* __restrict__ cosb,
                                                   const float* __restrict__ sinb,
                                                   __hip_bfloat16* __restrict__ skv) {
  int t = blockIdx.x, tid = threadIdx.x;
  __hip_bfloat16* out = skv + (long long)t * 576;
  if (t == T_) { for (int i = tid; i < 576; i += 256) out[i] = __float2bfloat16(0.f); return; }
  const float* row = ckv + (long long)t * 576;
  float ss = 0.f;
  for (int i = tid; i < 512; i += 256) { float v = row[i]; ss += v * v; }
  __shared__ float red[4];
  ss = wave_sum64(ss);
  if ((tid & 63) == 0) red[tid >> 6] = ss;
  __syncthreads();
  float sc = rsqrtf((red[0] + red[1] + red[2] + red[3]) / 512.f + 1e-6f);
  for (int i = tid; i < 512; i += 256) out[i] = __float2bfloat16(row[i] * sc * g[i]);
  if (tid < 64) {
    int j = tid, j2 = tid & 31;
    float c = cosb[t * 64 + j], s = sinb[t * 64 + j];
    float a = row[512 + 2 * j2], b = row[512 + 2 * j2 + 1];
    out[512 + j] = __float2bfloat16((j < 32) ? (a * c - b * s) : (a * s + b * c));
  }
}

// ================= rope in-place on qi heads (fp32) =================
__global__ __launch_bounds__(64) void rope_qi_k(float* qi, const float* __restrict__ cosb,
                                                const float* __restrict__ sinb) {
  int b = blockIdx.x, t = b >> 4, j = threadIdx.x, j2 = j & 31;
  float* x = qi + (long long)b * DI_;
  float c = cosb[t * 64 + j], s = sinb[t * 64 + j];
  float a = x[2 * j2], bb = x[2 * j2 + 1];
  float o = (j < 32) ? (a * c - bb * s) : (a * s + bb * c);
  x[j] = o;
}

// ================= ki: LayerNorm then rope, in-place (fp32) =================
__global__ __launch_bounds__(128) void ki_ln_rope_k(float* kbuf, const float* __restrict__ w,
                                                    const float* __restrict__ bia,
                                                    const float* __restrict__ cosb,
                                                    const float* __restrict__ sinb) {
  int t = blockIdx.x, i = threadIdx.x;
  float* row = kbuf + (long long)t * DI_;
  float x = row[i];
  __shared__ float red[2];
  float s1 = wave_sum64(x);
  if ((i & 63) == 0) red[i >> 6] = s1;
  __syncthreads();
  float mean = (red[0] + red[1]) / 128.f;
  float d = x - mean;
  __syncthreads();
  float s2 = wave_sum64(d * d);
  if ((i & 63) == 0) red[i >> 6] = s2;
  __syncthreads();
  float var = (red[0] + red[1]) / 128.f;
  float y = d * rsqrtf(var + 1e-6f) * w[i] + bia[i];
  __shared__ float rowl[128];
  rowl[i] = y;
  __syncthreads();
  float outv = y;
  if (i < 64) {
    int j2 = i & 31;
    float c = cosb[t * 64 + i], s = sinb[t * 64 + i];
    float a = rowl[2 * j2], b = rowl[2 * j2 + 1];
    outv = (i < 32) ? (a * c - b * s) : (a * s + b * c);
  }
  row[i] = outv;
}

// ================= rope q_full tail (bf16 in) -> sq_bf[...,512:576] =================
__global__ __launch_bounds__(64) void rope_q_sq_k(const __hip_bfloat16* __restrict__ qfull,
                                                  const float* __restrict__ cosb,
                                                  const float* __restrict__ sinb,
                                                  __hip_bfloat16* __restrict__ sq) {
  int b = blockIdx.x, t = b >> 4, h = b & 15, j = threadIdx.x, j2 = j & 31;
  const __hip_bfloat16* x = qfull + (long long)t * 3072 + h * 192 + 128;
  float c = cosb[t * 64 + j], s = sinb[t * 64 + j];
  float a = __bfloat162float(x[2 * j2]), bb = __bfloat162float(x[2 * j2 + 1]);
  float o = (j < 32) ? (a * c - bb * s) : (a * s + bb * c);
  sq[((long long)t * H_ + h) * 576 + 512 + j] = __float2bfloat16(o);
}

// ================= w = hidden @ i_wproj.T (fp32) =================
__global__ __launch_bounds__(256) void wproj_k(const float* __restrict__ hidden,
                                               const float* __restrict__ wp,
                                               float* __restrict__ out) {
  int wave = threadIdx.x >> 6, lane = threadIdx.x & 63;
  int t = blockIdx.x * 4 + wave;
  const float4* x4 = (const float4*)(hidden + (long long)t * 2048);
  float acc[16] = {};
  for (int c = lane; c < 512; c += 64) {
    float4 xv = x4[c];
#pragma unroll
    for (int h = 0; h < 16; ++h) {
      float4 wv = ((const float4*)(wp + h * 2048))[c];
      acc[h] += xv.x * wv.x + xv.y * wv.y + xv.z * wv.z + xv.w * wv.w;
    }
  }
#pragma unroll
  for (int h = 0; h < 16; ++h) {
    float s = wave_sum64(acc[h]);
    if (lane == 0) out[t * 16 + h] = s;
  }
}

// ========== exact radix-select top-256 — keys in registers, ballot-aggregated atomics ======
__global__ __launch_bounds__(256) void topk_k(const float* __restrict__ scores,
                                              int* __restrict__ indices)
{
  __shared__ unsigned s_hist[256];
  __shared__ unsigned s_wsum[4];
  __shared__ unsigned s_binsel[2];
  __shared__ unsigned s_cnt;
  const int t = blockIdx.x, tid = threadIdx.x;
  const int wave = tid >> 6, lane = tid & 63;
  const int i0 = tid * 4;
  if (tid == 0) s_cnt = 0;

  float4 sv = ((const float4*)(scores + t * T_))[tid];
  float f[4] = {sv.x, sv.y, sv.z, sv.w};
  unsigned key[4];
#pragma unroll
  for (int j = 0; j < 4; ++j) {
    unsigned u = __float_as_uint(f[j]);
    key[j] = (u & 0x80000000u) ? ~u : (u | 0x80000000u);
  }

  unsigned prefix = 0, Gprev = 0;
  for (int lvl = 0; lvl < 4; ++lvl) {
    const int shift = 24 - 8 * lvl;
    s_hist[tid] = 0;
    __syncthreads();
#pragma unroll
    for (int j = 0; j < 4; ++j) {
      unsigned k = key[j];
      bool part = (lvl == 0) || ((k >> (shift + 8)) == prefix);
      unsigned bin = (k >> shift) & 255u;
      unsigned long long mask = __ballot(part);
#pragma unroll
      for (int b = 0; b < 8; ++b) {
        unsigned long long bal = __ballot((bin >> b) & 1u);
        mask &= ((bin >> b) & 1u) ? bal : ~bal;
      }
      if (part && lane == (__ffsll((long long)mask) - 1))
        atomicAdd(&s_hist[bin], (unsigned)__popcll(mask));
    }
    __syncthreads();
    unsigned h = s_hist[255 - tid];
    unsigned sc_ = h;
    for (int off = 1; off < 64; off <<= 1) {
      unsigned v = __shfl_up(sc_, off);
      if (lane >= off) sc_ += v;
    }
    if (lane == 63) s_wsum[wave] = sc_;
    __syncthreads();
    unsigned wo = 0;
    for (int w = 0; w < wave; ++w) wo += s_wsum[w];
    unsigned incl = sc_ + wo, excl = incl - h;
    unsigned Rn = 256 - Gprev;
    if (excl < Rn && Rn <= incl) { s_binsel[0] = 255 - (unsigned)tid; s_binsel[1] = excl; }
    __syncthreads();
    prefix = (prefix << 8) | s_binsel[0];
    Gprev += s_binsel[1];
  }
  const unsigned thr = prefix;
  const unsigned Rq = 256 - Gprev;
  const unsigned negfkey = ~__float_as_uint(NEGF);

  unsigned eqc = 0;
#pragma unroll
  for (int j = 0; j < 4; ++j) eqc += (key[j] == thr) ? 1u : 0u;
  unsigned esc = eqc;
  for (int off = 1; off < 64; off <<= 1) {
    unsigned v = __shfl_up(esc, off);
    if (lane >= off) esc += v;
  }
  if (lane == 63) s_wsum[wave] = esc;
  __syncthreads();
  unsigned eo = 0;
  for (int w = 0; w < wave; ++w) eo += s_wsum[w];
  unsigned rank = esc + eo - eqc;

#pragma unroll
  for (int j = 0; j < 4; ++j) {
    unsigned k = key[j];
    int outv = (k == negfkey) ? T_ : (i0 + j);
    bool gt = (k > thr);
    unsigned long long bal = __ballot(gt);
    if (bal) {
      int leader = __ffsll((long long)bal) - 1;
      unsigned base = 0;
      if (lane == leader) base = atomicAdd(&s_cnt, (unsigned)__popcll(bal));
      base = (unsigned)__shfl((int)base, leader);
      if (gt) {
        unsigned pre = (unsigned)__popcll(bal & ((1ull << lane) - 1ull));
        indices[t * TOPK_ + base + pre] = outv;
      }
    }
    if (!gt && k == thr) {
      if (rank < Rq) indices[t * TOPK_ + Gprev + rank] = outv;
      rank++;
    }
  }
}

// ========= MFMA gathered attention — 512 thr; barrier-free swizzled QK pipeline ==========
// QK K-tiles are WAVE-PRIVATE (wave w stages+reads only rows [w*32,w*32+32)), so the
// per-kstep barriers are unnecessary: per-wave vmcnt ordering suffices. 36 barriers -> 1.
// Chunk XOR-swizzle (slot = chunk ^ ((row>>1)&3), applied on the per-lane GLL *source*,
// linear dest) makes the [row][32] ds_read_b128 pattern bank-conflict-free.
#define SP_LD 257
#define PB_LD 264
#define VT_LD 264
__global__ __launch_bounds__(512) void attn_k(
    const short* __restrict__ sq, const short* __restrict__ skv,
    const int* __restrict__ indices, __hip_bfloat16* __restrict__ attn_out)
{
  __shared__ int s_ind[TOPK_];
  __shared__ __align__(16) char s_un[76096];
  short* s_q  = (short*)s_un;                  // [18][16][32] = 18432 B (QK)
  short* s_k  = (short*)(s_un + 18432);        // [2][256][32] = 32768 B (QK)
  float* s_p  = (float*)(s_un + 51200);        // [16][SP_LD]  = 16448 B (QK out .. pack)
  short* s_vt = (short*)s_un;                  // [2][64][VT_LD] = 67584 B (PV)
  short* s_pb = (short*)(s_un + 67648);        // [16][PB_LD]  =  8448 B (disjoint)
  const int t = blockIdx.x, tid = threadIdx.x;
  const int wave = tid >> 6, lane = tid & 63;
  const int m0 = lane & 15, quad = lane >> 4;
  if (tid < TOPK_) s_ind[tid] = indices[t * TOPK_ + tid];
  __syncthreads();

  // ---- stage Q [18 ksteps][16 rows][32 shorts], chunk-swizzled source ----
  {
#pragma unroll
    for (int n = 0; n < 2; ++n) {
      const int c = n * 512 + tid;
      const int qks = c >> 6, qrow = (c >> 2) & 15;
      const int qch = (c & 3) ^ ((qrow >> 1) & 3);
      GLL(sq + ((long long)t * H_ + qrow) * 576 + qks * 32 + qch * 8, s_q + c * 8);
    }
    if (tid < 128) {
      const int c = 1024 + tid;
      const int qks = c >> 6, qrow = (c >> 2) & 15;
      const int qch = (c & 3) ^ ((qrow >> 1) & 3);
      GLL(sq + ((long long)t * H_ + qrow) * 576 + qks * 32 + qch * 8, s_q + c * 8);
    }
  }

  // ---- QK^T: barrier-free per-wave GLL pipeline; each wave owns 32 KV rows ----
  {
    const int jb = wave * 32;
    const int rowA = lane >> 2;                       // 0..15
    const int chA = (lane & 3) ^ ((rowA >> 1) & 3);   // swizzled source chunk
    const int rA = s_ind[jb + rowA];
    const int rB = s_ind[jb + 16 + rowA];             // (16+rowA)>>1 & 3 == (rowA>>1)&3
    const short* pA = skv + (long long)rA * 576 + chA * 8;
    const short* pB = skv + (long long)rB * 576 + chA * 8;
    short* ldsA = s_k + wave * 1024 + lane * 8;       // wave-linear dest (base + lane*16B)
#define STAGE_K(buf, kstep) \
    GLL(pA + (kstep) * 32, ldsA + (buf) * 8192); \
    GLL(pB + (kstep) * 32, ldsA + (buf) * 8192 + 512);
    f32x4 qacc[2] = {};
    STAGE_K(0, 0);
    asm volatile("s_waitcnt vmcnt(0)" ::: "memory");
    __syncthreads();                                  // Q staged by all threads
    const int sl = (quad ^ ((m0 >> 1) & 3)) * 8;      // swizzled read slot
    for (int ks = 0; ks < 18; ++ks) {
      const int cur = ks & 1;
      if (ks + 1 < 18) {
        STAGE_K(cur ^ 1, ks + 1);
        asm volatile("s_waitcnt vmcnt(2)" ::: "memory");
      } else {
        asm volatile("s_waitcnt vmcnt(0)" ::: "memory");
      }
      bfrag_t aq = *(const bfrag_t*)(s_q + ks * 512 + m0 * 32 + sl);
#pragma unroll
      for (int j = 0; j < 2; ++j) {
        bfrag_t bq = *(const bfrag_t*)(s_k + cur * 8192 + (jb + j * 16 + m0) * 32 + sl);
        qacc[j] = __builtin_amdgcn_mfma_f32_16x16x32_bf16(aq, bq, qacc[j], 0, 0, 0);
      }
    }
#undef STAGE_K
    const float scale = 0.07216878364870322f;
#pragma unroll
    for (int j = 0; j < 2; ++j) {
      int key = jb + j * 16 + m0;
      bool msk = (s_ind[key] == T_);
#pragma unroll
      for (int r = 0; r < 4; ++r)
        s_p[(quad * 4 + r) * SP_LD + key] = msk ? NEGF : qacc[j][r] * scale;
    }
  }
  __syncthreads();

  // ---- softmax (2 heads per wave) ----
  for (int h = wave * 2; h < wave * 2 + 2; ++h) {
    float* ph = s_p + h * SP_LD;
    float m = -3.4e38f;
    for (int j = lane; j < TOPK_; j += 64) m = fmaxf(m, ph[j]);
#pragma unroll
    for (int off = 32; off; off >>= 1) m = fmaxf(m, __shfl_xor(m, off));
    float sum = 0.f;
    for (int j = lane; j < TOPK_; j += 64) {
      float e = __expf(ph[j] - m);
      ph[j] = e; sum += e;
    }
    sum = wave_sum64(sum);
    float inv = 1.f / sum;
    for (int j = lane; j < TOPK_; j += 64) ph[j] *= inv;
  }
  __syncthreads();

  // ---- pack P -> bf16 (s_pb fully disjoint) ----
  {
    const int col = tid & 255, h0 = tid >> 8;
#pragma unroll
    for (int h = 0; h < 8; ++h) {
      const int hh = h0 + h * 2;
      s_pb[hh * PB_LD + col] =
          (short)__bfloat16_as_ushort(__float2bfloat16(s_p[hh * SP_LD + col]));
    }
  }
  __syncthreads();

  bfrag_t apf[8];
#pragma unroll
  for (int kk = 0; kk < 8; ++kk)
    apf[kk] = *(const bfrag_t*)(s_pb + m0 * PB_LD + kk * 32 + quad * 8);

  // ---- PV: group = wave>>2 handles c in [grp*4, grp*4+4) with its own s_vt ----
  const int grp = wave >> 2, gw = wave & 3;
  short* svt = s_vt + grp * (64 * VT_LD);
  const int r8 = (tid >> 3) & 31;   // row slot within 256-thread group
  const int bb = tid & 7;           // 16B chunk within the 128B slab

  for (int cc = 0; cc < 4; ++cc) {
    const int c = grp * 4 + cc;
    __syncthreads();   // apf reads (first iter) / prev MFMA reads done; safe to overwrite svt
#pragma unroll
    for (int rep = 0; rep < 8; ++rep) {
      const int kv = r8 + 32 * rep;
      const int row = s_ind[kv];
      bfrag_t v = *(const bfrag_t*)(skv + (long long)row * 576 + c * 64 + bb * 8);
      const int colx = kv ^ (bb << 3);
#pragma unroll
      for (int j = 0; j < 8; ++j)
        svt[(bb * 8 + j) * VT_LD + colx] = v[j];
    }
    __syncthreads();
    const int d = gw * 16 + m0;
    const short* vrow = svt + d * VT_LD;
    const int sx = (d >> 3) << 3;
    f32x4 oacc = {0.f, 0.f, 0.f, 0.f};
#pragma unroll
    for (int kk = 0; kk < 8; ++kk) {
      bfrag_t bv = *(const bfrag_t*)(vrow + ((kk * 32 + quad * 8) ^ sx));
      oacc = __builtin_amdgcn_mfma_f32_16x16x32_bf16(apf[kk], bv, oacc, 0, 0, 0);
    }
    const int col = c * 64 + d;
#pragma unroll
    for (int r = 0; r < 4; ++r)
      attn_out[((long long)t * H_ + quad * 4 + r) * 512 + col] = __float2bfloat16(oacc[r]);
  }
}

extern "C" void kernel_launch(void* const* d_in, const int* in_sizes, int n_in,
                              void* d_out, int out_size, void* d_ws, size_t ws_size,
                              hipStream_t stream) {
  const float* hidden  = (const float*)d_in[0];
  const float* cosb    = (const float*)d_in[1];
  const float* sinb    = (const float*)d_in[2];
  const int*   ks      = (const int*)d_in[3];
  const int*   ke      = (const int*)d_in[4];
  const float* w_qa    = (const float*)d_in[5];
  const float* g_qa    = (const float*)d_in[6];
  const float* w_qb    = (const float*)d_in[7];
  const float* w_kva   = (const float*)d_in[8];
  const float* g_kva   = (const float*)d_in[9];
  const float* w_kvb   = (const float*)d_in[10];
  const float* w_o     = (const float*)d_in[11];
  const float* i_wqb   = (const float*)d_in[12];
  const float* i_wk    = (const float*)d_in[13];
  const float* i_ln_w  = (const float*)d_in[14];
  const float* i_ln_b  = (const float*)d_in[15];
  const float* i_wproj = (const float*)d_in[16];
  float* out = (float*)d_out;
  (void)in_sizes; (void)n_in; (void)out_size; (void)ws_size;

  // ---- workspace (bytes), lifetime-overlapped (layout verified R6) ----
  char* ws = (char*)d_ws;
  __hip_bfloat16* hid_hi  = (__hip_bfloat16*)(ws + 0);
  __hip_bfloat16* hid_lo  = (__hip_bfloat16*)(ws + 4194304);
  float*          q_lat   = (float*)(ws + 8388608);
  __hip_bfloat16* qi_hi   = (__hip_bfloat16*)(ws + 8388608);    // over dead q_lat
  __hip_bfloat16* qlat_hi = (__hip_bfloat16*)(ws + 14680064);
  __hip_bfloat16* qlat_lo = (__hip_bfloat16*)(ws + 17825792);
  float*          qi      = (float*)(ws + 20971520);
  float*          scoresb = (float*)(ws + 20971520);            // over dead qi (post-decomp)
  float*          kib     = (float*)(ws + 29360128);
  float*          wbuf    = (float*)(ws + 29884416);
  float*          ckv     = (float*)(ws + 29949952);
  __hip_bfloat16* qi_lo   = (__hip_bfloat16*)(ws + 29949952);   // over dead ckv
  __hip_bfloat16* ki_hi   = (__hip_bfloat16*)(ws + 34144256);
  __hip_bfloat16* ki_lo   = (__hip_bfloat16*)(ws + 34406400);
  __hip_bfloat16* sq_bf   = (__hip_bfloat16*)(ws + 0);
  __hip_bfloat16* o_bf    = (__hip_bfloat16*)(ws + 0);
  __hip_bfloat16* W       = (__hip_bfloat16*)(ws + 37748736);
  __hip_bfloat16* skv_bf  = (__hip_bfloat16*)(ws + 47185920);
  int*            idxb    = (int*)(ws + 48366720);
  __hip_bfloat16* E       = (__hip_bfloat16*)(ws + 49415296);

  dim3 blk(256);
  const short* Ws = (const short*)W;
  const short* Es = (const short*)E;

  decomp_k<<<2048, blk, 0, stream>>>(hidden, hid_hi, hid_lo, 524288);

  // ---- q_lat = hidden @ w_qa^T (split-K=4: 384 blocks) ----
  decomp_k<<<3072, blk, 0, stream>>>(w_qa, W, E, 786432);
  zero_k<<<1536, blk, 0, stream>>>((float4*)q_lat, 393216);
  gemm3_k<<<dim3(12, 8, 4), blk, 0, stream>>>(
      (const short*)hid_hi, (const short*)hid_lo, HID_, Ws, Es, HID_, q_lat, LQ_, LQ_, 512);
  rms_inplace_k<<<T_, blk, 0, stream>>>(q_lat, g_qa, LQ_);

  // ---- ckv = hidden @ w_kva^T (split-K=4: 160 blocks) ----
  cast_pad_k<<<1280, blk, 0, stream>>>(w_kva, W, 576, 512, 640);
  zero_k<<<576, blk, 0, stream>>>((float4*)ckv, 147456);
  gemm_bfs_k<<<dim3(5, 8, 4), blk, 0, stream>>>(
      (const short*)hid_hi, HID_, Ws, HID_, ckv, 576, 576, 512);
  skv_build_k<<<T_ + 1, blk, 0, stream>>>(ckv, g_kva, cosb, sinb, skv_bf);

  decomp_k<<<1536, blk, 0, stream>>>(q_lat, qlat_hi, qlat_lo, 393216);

  // ---- qi = q_lat @ i_wqb^T (split-K=4: 512 blocks) ----
  decomp_k<<<3072, blk, 0, stream>>>(i_wqb, W, E, 786432);
  zero_k<<<2048, blk, 0, stream>>>((float4*)qi, 524288);
  gemm3_k<<<dim3(16, 8, 4), blk, 0, stream>>>(
      (const short*)qlat_hi, (const short*)qlat_lo, LQ_, Ws, Es, LQ_, qi, HI_ * DI_, HI_ * DI_, 384);
  rope_qi_k<<<T_ * HI_, dim3(64), 0, stream>>>(qi, cosb, sinb);
  decomp_k<<<2048, blk, 0, stream>>>(qi, qi_hi, qi_lo, 524288);

  // ---- kib = hidden @ i_wk^T (split-K=16: 128 blocks) ----
  decomp_k<<<256, blk, 0, stream>>>(i_wk, W, E, 65536);
  zero_k<<<128, blk, 0, stream>>>((float4*)kib, 32768);
  gemm3_k<<<dim3(1, 8, 16), blk, 0, stream>>>(
      (const short*)hid_hi, (const short*)hid_lo, HID_, Ws, Es, HID_, kib, DI_, DI_, 128);
  ki_ln_rope_k<<<T_, dim3(128), 0, stream>>>(kib, i_ln_w, i_ln_b, cosb, sinb);
  decomp_k<<<128, blk, 0, stream>>>(kib, ki_hi, ki_lo, 32768);

  wproj_k<<<256, blk, 0, stream>>>(hidden, i_wproj, wbuf);

  // ---- indexer: GEMM-shaped scores (GLL pipeline) then register-key radix select ----
  score_gemm_k<<<dim3(8, 128), blk, 0, stream>>>(
      (const short*)qi_hi, (const short*)qi_lo, (const short*)ki_hi, (const short*)ki_lo,
      wbuf, ks, ke, scoresb);
  topk_k<<<T_, blk, 0, stream>>>(scoresb, idxb);

  cast_bf16_k<<<4608, blk, 0, stream>>>(w_qb, W, 1179648);
  gemm_bf_k<__hip_bfloat16><<<dim3(24, 8, 1), blk, 0, stream>>>(
      (const short*)qlat_hi, LQ_, 0, Ws, LQ_, 0, (__hip_bfloat16*)E, H_ * DQ_, 0, H_ * DQ_, LQ_);
  rope_q_sq_k<<<T_ * H_, dim3(64), 0, stream>>>(E, cosb, sinb, sq_bf);

  wkn_t_k<<<dim3(2, 8, 16), blk, 0, stream>>>(w_kvb, W);
  gemm_bf_k<__hip_bfloat16><<<dim3(4, 8, 16), blk, 0, stream>>>(
      Es, H_ * DQ_, 192, Ws, DI_, 65536, sq_bf, H_ * 576, 576, LKV_, DN_);

  attn_k<<<T_, dim3(512), 0, stream>>>((const short*)sq_bf, (const short*)skv_bf, idxb, E);

  wv_cast_k<<<4096, blk, 0, stream>>>(w_kvb, W);
  gemm_bf_k<__hip_bfloat16><<<dim3(1, 8, 16), blk, 0, stream>>>(
      Es, H_ * LKV_, 512, Ws, LKV_, 65536, o_bf, H_ * DV_, 128, DV_, LKV_);

  // ---- out = o_bf @ w_o^T (split-K=4: 512 blocks) ----
  cast_bf16_k<<<4096, blk, 0, stream>>>(w_o, W, 1048576);
  zero_k<<<2048, blk, 0, stream>>>((float4*)out, 524288);
  gemm_bfs_k<<<dim3(16, 8, 4), blk, 0, stream>>>(
      (const short*)o_bf, H_ * DV_, Ws, H_ * DV_, out, HID_, HID_, 512);
}